// Round 4
// baseline (779.162 us; speedup 1.0000x reference)
//
#include <hip/hip_runtime.h>

// GALA graph autoencoder on MI355X — round 4.
// - GEMM: float4-k inner loop (ds_read_b128), strided row ownership (bank-conflict-free),
//         epilogue fuses bias/relu/row-scale by dinv.
// - Propagation: weightless gather — prop = dinv ⊙ (A^T (dinv ⊙ h)); per-edge loop is
//         {load src, load float4 h, add}. Nodes processed in degree-sorted order so all
//         lane-groups in a wave have equal trip counts (no divergence).

static inline int ceil_div(int a, int b) { return (a + b - 1) / b; }

#define SCAN_BLK 256
#define NBINS 64

// ---------------- degree / norm / histogram ----------------

__global__ void deg_kernel(const int* __restrict__ col, int* __restrict__ deg, int E) {
    int e = blockIdx.x * blockDim.x + threadIdx.x;
    if (e < E) atomicAdd(&deg[col[e]], 1);
}

__global__ void dinv_hist_kernel(const int* __restrict__ deg, float* __restrict__ dinv_s,
                                 float* __restrict__ dinv_h, int* __restrict__ binc, int n) {
    __shared__ int hb[NBINS];
    if (threadIdx.x < NBINS) hb[threadIdx.x] = 0;
    __syncthreads();
    int i = blockIdx.x * blockDim.x + threadIdx.x;
    if (i < n) {
        int d = deg[i];
        float df = (float)d;
        dinv_s[i] = rsqrtf(df + 1.0f);  // smooth: deg = indeg + 1
        dinv_h[i] = rsqrtf(df + 2.0f);  // sharp:  deg = indeg + 2
        atomicAdd(&hb[d < NBINS ? d : NBINS - 1], 1);
    }
    __syncthreads();
    if (threadIdx.x < NBINS) atomicAdd(&binc[threadIdx.x], hb[threadIdx.x]);
}

// 1 block, NBINS threads: exclusive scan of binc -> bincur
__global__ void bin_scan_kernel(const int* __restrict__ binc, int* __restrict__ bincur) {
    __shared__ int s[NBINS];
    int t = threadIdx.x;
    int v = binc[t];
    s[t] = v;
    __syncthreads();
    for (int st = 1; st < NBINS; st <<= 1) {
        int add = (t >= st) ? s[t - st] : 0;
        __syncthreads();
        s[t] += add;
        __syncthreads();
    }
    bincur[t] = s[t] - v;  // exclusive
}

__global__ void order_kernel(const int* __restrict__ deg, int* __restrict__ bincur,
                             int* __restrict__ order, int n) {
    int i = blockIdx.x * blockDim.x + threadIdx.x;
    if (i < n) {
        int b = deg[i]; if (b >= NBINS) b = NBINS - 1;
        int p = atomicAdd(&bincur[b], 1);
        order[p] = i;
    }
}

// ---------------- CSR build: block scan of degrees ----------------

__global__ void blk_reduce_kernel(const int* __restrict__ deg, int* __restrict__ bsum, int n) {
    __shared__ int s[SCAN_BLK];
    int i = blockIdx.x * SCAN_BLK + threadIdx.x;
    s[threadIdx.x] = (i < n) ? deg[i] : 0;
    __syncthreads();
    for (int st = SCAN_BLK / 2; st > 0; st >>= 1) {
        if (threadIdx.x < st) s[threadIdx.x] += s[threadIdx.x + st];
        __syncthreads();
    }
    if (threadIdx.x == 0) bsum[blockIdx.x] = s[0];
}

__global__ void bsum_scan_kernel(int* bsum, int nb) {
    __shared__ int s[1024];
    int t = threadIdx.x;
    int v0 = (t < nb) ? bsum[t] : 0;
    s[t] = v0;
    __syncthreads();
    for (int st = 1; st < 1024; st <<= 1) {
        int add = (t >= st) ? s[t - st] : 0;
        __syncthreads();
        s[t] += add;
        __syncthreads();
    }
    if (t < nb) bsum[t] = s[t] - v0;  // exclusive
}

__global__ void offs_kernel(const int* __restrict__ deg, const int* __restrict__ bpre,
                            int* __restrict__ offs, int n) {
    __shared__ int s[SCAN_BLK];
    int i = blockIdx.x * SCAN_BLK + threadIdx.x;
    int t = threadIdx.x;
    int v0 = (i < n) ? deg[i] : 0;
    s[t] = v0;
    __syncthreads();
    for (int st = 1; st < SCAN_BLK; st <<= 1) {
        int add = (t >= st) ? s[t - st] : 0;
        __syncthreads();
        s[t] += add;
        __syncthreads();
    }
    if (i <= n) offs[i] = bpre[blockIdx.x] + s[t] - v0;
}

__global__ void csr_fill_kernel(const int* __restrict__ row, const int* __restrict__ col,
                                int* __restrict__ cursor, int* __restrict__ src, int E) {
    int e = blockIdx.x * blockDim.x + threadIdx.x;
    if (e >= E) return;
    int p = atomicAdd(&cursor[col[e]], 1);
    src[p] = row[e];
}

// ---------------- register-blocked GEMM ----------------
// out[n,DOUT] = g( f(A[n,DIN]) @ W[DIN,DOUT] (+bias) (relu) ) * (rs[row]?)
// 256 threads; A-tile in LDS; thread owns RPT strided rows x 4 cols; W via L1.

template <int DIN, int DOUT, int RPT, bool RELU_IN, bool ADD_BIAS, bool RELU_OUT, bool SCALE_ROW>
__global__ __launch_bounds__(256) void gemm_tile(const float* __restrict__ A,
                                                 const float* __restrict__ W,
                                                 const float* __restrict__ bias,
                                                 const float* __restrict__ rs,
                                                 float* __restrict__ out, int n) {
    constexpr int CG  = DOUT / 4;     // col groups of 4
    constexpr int RPI = 256 / CG;     // row stride between a thread's rows
    constexpr int BM  = RPI * RPT;    // rows per block
    constexpr int LD  = DIN + 4;      // padded LDS stride
    constexpr int Q   = DIN / 4;      // float4 per row
    __shared__ float As[BM * LD];

    const int row0 = blockIdx.x * BM;
    for (int i = threadIdx.x; i < BM * Q; i += 256) {
        int r = i / Q, j = i % Q;
        float4 v = make_float4(0.f, 0.f, 0.f, 0.f);
        if (row0 + r < n) v = *(const float4*)(A + (size_t)(row0 + r) * DIN + j * 4);
        if (RELU_IN) {
            v.x = fmaxf(v.x, 0.f); v.y = fmaxf(v.y, 0.f);
            v.z = fmaxf(v.z, 0.f); v.w = fmaxf(v.w, 0.f);
        }
        *(float4*)(&As[r * LD + j * 4]) = v;
    }
    __syncthreads();

    const int cgid = threadIdx.x % CG;
    const int rsub = threadIdx.x / CG;
    float4 acc[RPT];
#pragma unroll
    for (int rr = 0; rr < RPT; ++rr) acc[rr] = make_float4(0.f, 0.f, 0.f, 0.f);

#pragma unroll 4
    for (int k4 = 0; k4 < Q; ++k4) {
        const float4* wp = (const float4*)(W + (size_t)k4 * 4 * DOUT) + cgid;
        float4 w0 = wp[0];
        float4 w1 = wp[CG];
        float4 w2 = wp[2 * CG];
        float4 w3 = wp[3 * CG];
#pragma unroll
        for (int rr = 0; rr < RPT; ++rr) {
            float4 a = *(const float4*)(&As[(rsub + rr * RPI) * LD + k4 * 4]);
            acc[rr].x = fmaf(a.x, w0.x, fmaf(a.y, w1.x, fmaf(a.z, w2.x, fmaf(a.w, w3.x, acc[rr].x))));
            acc[rr].y = fmaf(a.x, w0.y, fmaf(a.y, w1.y, fmaf(a.z, w2.y, fmaf(a.w, w3.y, acc[rr].y))));
            acc[rr].z = fmaf(a.x, w0.z, fmaf(a.y, w1.z, fmaf(a.z, w2.z, fmaf(a.w, w3.z, acc[rr].z))));
            acc[rr].w = fmaf(a.x, w0.w, fmaf(a.y, w1.w, fmaf(a.z, w2.w, fmaf(a.w, w3.w, acc[rr].w))));
        }
    }

    float4 b4 = make_float4(0.f, 0.f, 0.f, 0.f);
    if (ADD_BIAS) b4 = *(const float4*)(bias + cgid * 4);
#pragma unroll
    for (int rr = 0; rr < RPT; ++rr) {
        int row = row0 + rsub + rr * RPI;
        if (row >= n) continue;
        float4 o = acc[rr];
        if (ADD_BIAS) { o.x += b4.x; o.y += b4.y; o.z += b4.z; o.w += b4.w; }
        if (RELU_OUT) {
            o.x = fmaxf(o.x, 0.f); o.y = fmaxf(o.y, 0.f);
            o.z = fmaxf(o.z, 0.f); o.w = fmaxf(o.w, 0.f);
        }
        if (SCALE_ROW) {
            float sc = rs[row];
            o.x *= sc; o.y *= sc; o.z *= sc; o.w *= sc;
        }
        *(float4*)(out + (size_t)row * DOUT + cgid * 4) = o;
    }
}

// ---------------- propagation: weightless CSR gather ----------------
// input u is already dinv-scaled per row. For node c (taken from degree-sorted order):
//   S = sum_{e} f(u[src[e]]),  self = f(u[c])
//   smooth: t = dinv[c]*(S + self) (+bias)
//   sharp:  t = dinv[c]*(2*self - S) (+bias)
//   optional post-scale by ps[c] (to pre-scale for the NEXT sharp prop)

template <bool RELU_IN, bool SHARP, bool ADD_BIAS, bool POST_SCALE>
__global__ __launch_bounds__(256) void gather_kernel(
        const float* __restrict__ u, const int* __restrict__ offs,
        const int* __restrict__ src, const int* __restrict__ order,
        const float* __restrict__ dinv, const float* __restrict__ ps,
        const float* __restrict__ bias, float* __restrict__ out,
        int n, int dout, int dq_shift) {
    int idx = blockIdx.x * blockDim.x + threadIdx.x;
    int dq = 1 << dq_shift;           // dout/4
    int slot = idx >> dq_shift;
    if (slot >= n) return;
    int node = order[slot];
    int d4 = (idx & (dq - 1)) << 2;

    float4 self4 = *(const float4*)(u + (size_t)node * dout + d4);
    if (RELU_IN) {
        self4.x = fmaxf(self4.x, 0.f); self4.y = fmaxf(self4.y, 0.f);
        self4.z = fmaxf(self4.z, 0.f); self4.w = fmaxf(self4.w, 0.f);
    }
    float4 acc = make_float4(0.f, 0.f, 0.f, 0.f);
    int s = offs[node], e1 = offs[node + 1];
    for (int e = s; e < e1; ++e) {
        int r = src[e];
        float4 v = *(const float4*)(u + (size_t)r * dout + d4);
        if (RELU_IN) {
            v.x = fmaxf(v.x, 0.f); v.y = fmaxf(v.y, 0.f);
            v.z = fmaxf(v.z, 0.f); v.w = fmaxf(v.w, 0.f);
        }
        acc.x += v.x; acc.y += v.y; acc.z += v.z; acc.w += v.w;
    }
    float dv = dinv[node];
    float4 t;
    if (SHARP) {
        t.x = dv * (2.f * self4.x - acc.x); t.y = dv * (2.f * self4.y - acc.y);
        t.z = dv * (2.f * self4.z - acc.z); t.w = dv * (2.f * self4.w - acc.w);
    } else {
        t.x = dv * (acc.x + self4.x); t.y = dv * (acc.y + self4.y);
        t.z = dv * (acc.z + self4.z); t.w = dv * (acc.w + self4.w);
    }
    if (ADD_BIAS) {
        float4 b4 = *(const float4*)(bias + d4);
        t.x += b4.x; t.y += b4.y; t.z += b4.z; t.w += b4.w;
    }
    if (POST_SCALE) {
        float p = ps[node];
        t.x *= p; t.y *= p; t.z *= p; t.w *= p;
    }
    *(float4*)(out + (size_t)node * dout + d4) = t;
}

// ---------------- host orchestration ----------------

static int dq_shift_of(int dout) {
    int dq = dout >> 2, s = 0;
    while ((1 << s) < dq) ++s;
    return s;
}

extern "C" void kernel_launch(void* const* d_in, const int* in_sizes, int n_in,
                              void* d_out, int out_size, void* d_ws, size_t ws_size,
                              hipStream_t stream) {
    const int T = 128;
    const int n = in_sizes[0] / T;        // 100000
    const int E = in_sizes[1] / 2;        // 600000

    const float* x   = (const float*)d_in[0];
    const int* eidx  = (const int*)d_in[1];
    const int* row   = eidx;
    const int* col   = eidx + E;
    const float* We1 = (const float*)d_in[2];
    const float* be1 = (const float*)d_in[3];
    const float* We2 = (const float*)d_in[4];
    const float* be2 = (const float*)d_in[5];
    const float* We3 = (const float*)d_in[6];
    const float* be3 = (const float*)d_in[7];
    const float* Wd1 = (const float*)d_in[8];
    const float* bd1 = (const float*)d_in[9];
    const float* Wd2 = (const float*)d_in[10];
    const float* bd2 = (const float*)d_in[11];
    const float* Wd3 = (const float*)d_in[12];
    const float* bd3 = (const float*)d_in[13];
    float* out = (float*)d_out;

    // workspace layout (all 16B aligned)
    char* base = (char*)d_ws;
    int*   deg    = (int*)base;   base += (size_t)n * 4;
    int*   offs   = (int*)base;   base += (size_t)(n + 4) * 4;
    int*   cursor = (int*)base;   base += (size_t)(n + 4) * 4;
    int*   bsum   = (int*)base;   base += (size_t)1024 * 4;
    int*   binc   = (int*)base;   base += (size_t)NBINS * 4;
    int*   bincur = (int*)base;   base += (size_t)NBINS * 4;
    float* dinv_s = (float*)base; base += (size_t)n * 4;
    float* dinv_h = (float*)base; base += (size_t)n * 4;
    int*   order  = (int*)base;   base += (size_t)n * 4;
    int*   src    = (int*)base;   base += (size_t)E * 4;
    float* bufA   = (float*)base; base += (size_t)n * 64 * 4;
    float* bufB   = (float*)base; base += (size_t)n * 64 * 4;
    (void)ws_size;

    const int BLK = 256;
    const int nb = ceil_div(n + 1, SCAN_BLK);   // scan covers [0, n]

    // --- degrees, norms, degree-sort order ---
    hipMemsetAsync(deg, 0, (size_t)n * 4, stream);
    hipMemsetAsync(binc, 0, (size_t)NBINS * 4, stream);
    deg_kernel<<<ceil_div(E, BLK), BLK, 0, stream>>>(col, deg, E);
    dinv_hist_kernel<<<ceil_div(n, BLK), BLK, 0, stream>>>(deg, dinv_s, dinv_h, binc, n);
    bin_scan_kernel<<<1, NBINS, 0, stream>>>(binc, bincur);
    order_kernel<<<ceil_div(n, BLK), BLK, 0, stream>>>(deg, bincur, order, n);

    // --- CSR build ---
    blk_reduce_kernel<<<nb, SCAN_BLK, 0, stream>>>(deg, bsum, n);
    bsum_scan_kernel<<<1, 1024, 0, stream>>>(bsum, nb);
    offs_kernel<<<nb, SCAN_BLK, 0, stream>>>(deg, bsum, offs, n);
    hipMemcpyAsync(cursor, offs, (size_t)n * 4, hipMemcpyDeviceToDevice, stream);
    csr_fill_kernel<<<ceil_div(E, BLK), BLK, 0, stream>>>(row, col, cursor, src, E);

    auto gath_grid = [&](int dout) { return ceil_div(n * (dout >> 2), BLK); };

    // ================= encoder (smooth): GEMM(scale dinv_s) then gather =================
    // L1: u1 = dinv_s ⊙ (x @ We1); a1 = dinv_s[c](Σu1 + u1[c]) + be1
    gemm_tile<128, 64, 4, false, false, false, true><<<ceil_div(n, 64), BLK, 0, stream>>>(
        x, We1, nullptr, dinv_s, bufA, n);
    gather_kernel<false, false, true, false><<<gath_grid(64), BLK, 0, stream>>>(
        bufA, offs, src, order, dinv_s, nullptr, be1, bufB, n, 64, dq_shift_of(64));

    // L2: u2 = dinv_s ⊙ (relu(a1) @ We2); a2 = dinv_s[c](Σu2 + u2[c]) + be2
    gemm_tile<64, 32, 4, true, false, false, true><<<ceil_div(n, 128), BLK, 0, stream>>>(
        bufB, We2, nullptr, dinv_s, bufA, n);
    gather_kernel<false, false, true, false><<<gath_grid(32), BLK, 0, stream>>>(
        bufA, offs, src, order, dinv_s, nullptr, be2, bufB, n, 32, dq_shift_of(32));

    // L3: u3 = dinv_s ⊙ (relu(a2) @ We3); Z' = dinv_h ⊙ (dinv_s[c](Σu3+u3[c]) + be3)
    gemm_tile<32, 16, 4, true, false, false, true><<<ceil_div(n, 256), BLK, 0, stream>>>(
        bufB, We3, nullptr, dinv_s, bufA, n);
    gather_kernel<false, false, true, true><<<gath_grid(16), BLK, 0, stream>>>(
        bufA, offs, src, order, dinv_s, dinv_h, be3, bufB, n, 16, dq_shift_of(16));

    // ================= decoder (sharp): gather then GEMM(scale dinv_h) =================
    // L4: P_h(z) = dinv_h[c](2 relu(Z'[c]) - Σ relu(Z'[src])); u4 = dinv_h ⊙ relu(P@Wd1+bd1)
    gather_kernel<true, true, false, false><<<gath_grid(16), BLK, 0, stream>>>(
        bufB, offs, src, order, dinv_h, nullptr, nullptr, bufA, n, 16, dq_shift_of(16));
    gemm_tile<16, 32, 4, false, true, true, true><<<ceil_div(n, 128), BLK, 0, stream>>>(
        bufA, Wd1, bd1, dinv_h, bufB, n);

    // L5: P_h(h4) = dinv_h[c](2 u4[c] - Σ u4); u5 = dinv_h ⊙ relu(P@Wd2+bd2)
    gather_kernel<false, true, false, false><<<gath_grid(32), BLK, 0, stream>>>(
        bufB, offs, src, order, dinv_h, nullptr, nullptr, bufA, n, 32, dq_shift_of(32));
    gemm_tile<32, 64, 4, false, true, true, true><<<ceil_div(n, 64), BLK, 0, stream>>>(
        bufA, Wd2, bd2, dinv_h, bufB, n);

    // L6: P_h(h5) = dinv_h[c](2 u5[c] - Σ u5); out = P @ Wd3 + bd3
    gather_kernel<false, true, false, false><<<gath_grid(64), BLK, 0, stream>>>(
        bufB, offs, src, order, dinv_h, nullptr, nullptr, bufA, n, 64, dq_shift_of(64));
    gemm_tile<64, 128, 4, false, true, false, false><<<ceil_div(n, 32), BLK, 0, stream>>>(
        bufA, Wd3, bd3, nullptr, out, n);
}

// Round 5
// 410.137 us; speedup vs baseline: 1.8998x; 1.8998x over previous
//
#include <hip/hip_runtime.h>

// GALA graph autoencoder on MI355X — round 5.
// - Propagation: wave-per-node CSR gather. 64 lanes = ES edge-slots x DQ dim-groups;
//   trips = ceil(deg/ES) (no intra-wave divergence), shfl_xor slot-reduce,
//   fused self-loop/bias/post-scale. Weightless algebra: prop = dinv ⊙ (A^T (dinv ⊙ h)).
// - GEMM: float4-k inner loop (ds_read_b128), strided row ownership, W via L1,
//   epilogue fuses bias/relu/row-scale.
// - No sort, no bin atomics (round-4's order_kernel was 360us of atomic contention).

static inline int ceil_div(int a, int b) { return (a + b - 1) / b; }

#define SCAN_BLK 256

// ---------------- degree / norm precompute ----------------

__global__ void deg_kernel(const int* __restrict__ col, int* __restrict__ deg, int E) {
    int e = blockIdx.x * blockDim.x + threadIdx.x;
    if (e < E) atomicAdd(&deg[col[e]], 1);
}

__global__ void dinv_kernel(const int* __restrict__ deg, float* __restrict__ dinv_s,
                            float* __restrict__ dinv_h, int n) {
    int i = blockIdx.x * blockDim.x + threadIdx.x;
    if (i < n) {
        float d = (float)deg[i];
        dinv_s[i] = rsqrtf(d + 1.0f);  // smooth: deg = indeg + 1
        dinv_h[i] = rsqrtf(d + 2.0f);  // sharp:  deg = indeg + 2
    }
}

// ---------------- CSR build: block scan of degrees ----------------

__global__ void blk_reduce_kernel(const int* __restrict__ deg, int* __restrict__ bsum, int n) {
    __shared__ int s[SCAN_BLK];
    int i = blockIdx.x * SCAN_BLK + threadIdx.x;
    s[threadIdx.x] = (i < n) ? deg[i] : 0;
    __syncthreads();
    for (int st = SCAN_BLK / 2; st > 0; st >>= 1) {
        if (threadIdx.x < st) s[threadIdx.x] += s[threadIdx.x + st];
        __syncthreads();
    }
    if (threadIdx.x == 0) bsum[blockIdx.x] = s[0];
}

__global__ void bsum_scan_kernel(int* bsum, int nb) {
    __shared__ int s[1024];
    int t = threadIdx.x;
    int v0 = (t < nb) ? bsum[t] : 0;
    s[t] = v0;
    __syncthreads();
    for (int st = 1; st < 1024; st <<= 1) {
        int add = (t >= st) ? s[t - st] : 0;
        __syncthreads();
        s[t] += add;
        __syncthreads();
    }
    if (t < nb) bsum[t] = s[t] - v0;  // exclusive
}

__global__ void offs_kernel(const int* __restrict__ deg, const int* __restrict__ bpre,
                            int* __restrict__ offs, int n) {
    __shared__ int s[SCAN_BLK];
    int i = blockIdx.x * SCAN_BLK + threadIdx.x;
    int t = threadIdx.x;
    int v0 = (i < n) ? deg[i] : 0;
    s[t] = v0;
    __syncthreads();
    for (int st = 1; st < SCAN_BLK; st <<= 1) {
        int add = (t >= st) ? s[t - st] : 0;
        __syncthreads();
        s[t] += add;
        __syncthreads();
    }
    if (i <= n) offs[i] = bpre[blockIdx.x] + s[t] - v0;
}

__global__ void csr_fill_kernel(const int* __restrict__ row, const int* __restrict__ col,
                                int* __restrict__ cursor, int* __restrict__ src, int E) {
    int e = blockIdx.x * blockDim.x + threadIdx.x;
    if (e >= E) return;
    int p = atomicAdd(&cursor[col[e]], 1);
    src[p] = row[e];
}

// ---------------- register-blocked GEMM ----------------
// out[n,DOUT] = (f(A) @ W (+bias) (relu)) * (rs[row]?)

template <int DIN, int DOUT, int RPT, bool RELU_IN, bool ADD_BIAS, bool RELU_OUT, bool SCALE_ROW>
__global__ __launch_bounds__(256) void gemm_tile(const float* __restrict__ A,
                                                 const float* __restrict__ W,
                                                 const float* __restrict__ bias,
                                                 const float* __restrict__ rs,
                                                 float* __restrict__ out, int n) {
    constexpr int CG  = DOUT / 4;     // col groups of 4
    constexpr int RPI = 256 / CG;     // row stride between a thread's rows
    constexpr int BM  = RPI * RPT;    // rows per block
    constexpr int LD  = DIN + 4;      // padded LDS stride
    constexpr int Q   = DIN / 4;      // float4 per row
    __shared__ float As[BM * LD];

    const int row0 = blockIdx.x * BM;
    for (int i = threadIdx.x; i < BM * Q; i += 256) {
        int r = i / Q, j = i % Q;
        float4 v = make_float4(0.f, 0.f, 0.f, 0.f);
        if (row0 + r < n) v = *(const float4*)(A + (size_t)(row0 + r) * DIN + j * 4);
        if (RELU_IN) {
            v.x = fmaxf(v.x, 0.f); v.y = fmaxf(v.y, 0.f);
            v.z = fmaxf(v.z, 0.f); v.w = fmaxf(v.w, 0.f);
        }
        *(float4*)(&As[r * LD + j * 4]) = v;
    }
    __syncthreads();

    const int cgid = threadIdx.x % CG;
    const int rsub = threadIdx.x / CG;
    float4 acc[RPT];
#pragma unroll
    for (int rr = 0; rr < RPT; ++rr) acc[rr] = make_float4(0.f, 0.f, 0.f, 0.f);

#pragma unroll 4
    for (int k4 = 0; k4 < Q; ++k4) {
        const float4* wp = (const float4*)(W + (size_t)k4 * 4 * DOUT) + cgid;
        float4 w0 = wp[0];
        float4 w1 = wp[CG];
        float4 w2 = wp[2 * CG];
        float4 w3 = wp[3 * CG];
#pragma unroll
        for (int rr = 0; rr < RPT; ++rr) {
            float4 a = *(const float4*)(&As[(rsub + rr * RPI) * LD + k4 * 4]);
            acc[rr].x = fmaf(a.x, w0.x, fmaf(a.y, w1.x, fmaf(a.z, w2.x, fmaf(a.w, w3.x, acc[rr].x))));
            acc[rr].y = fmaf(a.x, w0.y, fmaf(a.y, w1.y, fmaf(a.z, w2.y, fmaf(a.w, w3.y, acc[rr].y))));
            acc[rr].z = fmaf(a.x, w0.z, fmaf(a.y, w1.z, fmaf(a.z, w2.z, fmaf(a.w, w3.z, acc[rr].z))));
            acc[rr].w = fmaf(a.x, w0.w, fmaf(a.y, w1.w, fmaf(a.z, w2.w, fmaf(a.w, w3.w, acc[rr].w))));
        }
    }

    float4 b4 = make_float4(0.f, 0.f, 0.f, 0.f);
    if (ADD_BIAS) b4 = *(const float4*)(bias + cgid * 4);
#pragma unroll
    for (int rr = 0; rr < RPT; ++rr) {
        int row = row0 + rsub + rr * RPI;
        if (row >= n) continue;
        float4 o = acc[rr];
        if (ADD_BIAS) { o.x += b4.x; o.y += b4.y; o.z += b4.z; o.w += b4.w; }
        if (RELU_OUT) {
            o.x = fmaxf(o.x, 0.f); o.y = fmaxf(o.y, 0.f);
            o.z = fmaxf(o.z, 0.f); o.w = fmaxf(o.w, 0.f);
        }
        if (SCALE_ROW) {
            float sc = rs[row];
            o.x *= sc; o.y *= sc; o.z *= sc; o.w *= sc;
        }
        *(float4*)(out + (size_t)row * DOUT + cgid * 4) = o;
    }
}

// ---------------- propagation: wave-per-node CSR gather ----------------
// u is already dinv-scaled per row. For node c:
//   S = sum_e f(u[src[e]]),  self = f(u[c])
//   smooth: t = dinv[c]*(S + self) (+bias)
//   sharp:  t = dinv[c]*(2*self - S) (+bias)
//   optional post-scale by ps[c] (pre-scales for the NEXT sharp prop).
// Wave layout: lane = slot*DQ + dg; slot in [0,ES), dg covers dims [4dg,4dg+4).

template <int DOUT, bool RELU_IN, bool SHARP, bool ADD_BIAS, bool POST_SCALE>
__global__ __launch_bounds__(256) void gather_wave(
        const float* __restrict__ u, const int* __restrict__ offs,
        const int* __restrict__ src, const float* __restrict__ dinv,
        const float* __restrict__ ps, const float* __restrict__ bias,
        float* __restrict__ out, int n) {
    constexpr int DQ = DOUT / 4;      // dim-groups (lanes per node-dim coverage)
    constexpr int ES = 64 / DQ;       // edge slots per wave
    const int wid = (blockIdx.x * blockDim.x + threadIdx.x) >> 6;   // node id
    if (wid >= n) return;
    const int lane = threadIdx.x & 63;
    const int dg   = lane % DQ;
    const int slot = lane / DQ;

    const int s  = offs[wid];
    const int e1 = offs[wid + 1];

    float4 acc = make_float4(0.f, 0.f, 0.f, 0.f);
    for (int e = s + slot; e < e1; e += ES) {
        int r = src[e];
        float4 v = *(const float4*)(u + (size_t)r * DOUT + dg * 4);
        if (RELU_IN) {
            v.x = fmaxf(v.x, 0.f); v.y = fmaxf(v.y, 0.f);
            v.z = fmaxf(v.z, 0.f); v.w = fmaxf(v.w, 0.f);
        }
        acc.x += v.x; acc.y += v.y; acc.z += v.z; acc.w += v.w;
    }
    // reduce across edge slots (lanes differing in bits >= log2(DQ))
#pragma unroll
    for (int m = DQ; m < 64; m <<= 1) {
        acc.x += __shfl_xor(acc.x, m, 64);
        acc.y += __shfl_xor(acc.y, m, 64);
        acc.z += __shfl_xor(acc.z, m, 64);
        acc.w += __shfl_xor(acc.w, m, 64);
    }

    if (slot == 0) {
        float4 self4 = *(const float4*)(u + (size_t)wid * DOUT + dg * 4);
        if (RELU_IN) {
            self4.x = fmaxf(self4.x, 0.f); self4.y = fmaxf(self4.y, 0.f);
            self4.z = fmaxf(self4.z, 0.f); self4.w = fmaxf(self4.w, 0.f);
        }
        float dv = dinv[wid];
        float4 t;
        if (SHARP) {
            t.x = dv * (2.f * self4.x - acc.x); t.y = dv * (2.f * self4.y - acc.y);
            t.z = dv * (2.f * self4.z - acc.z); t.w = dv * (2.f * self4.w - acc.w);
        } else {
            t.x = dv * (acc.x + self4.x); t.y = dv * (acc.y + self4.y);
            t.z = dv * (acc.z + self4.z); t.w = dv * (acc.w + self4.w);
        }
        if (ADD_BIAS) {
            float4 b4 = *(const float4*)(bias + dg * 4);
            t.x += b4.x; t.y += b4.y; t.z += b4.z; t.w += b4.w;
        }
        if (POST_SCALE) {
            float p = ps[wid];
            t.x *= p; t.y *= p; t.z *= p; t.w *= p;
        }
        *(float4*)(out + (size_t)wid * DOUT + dg * 4) = t;
    }
}

// ---------------- host orchestration ----------------

extern "C" void kernel_launch(void* const* d_in, const int* in_sizes, int n_in,
                              void* d_out, int out_size, void* d_ws, size_t ws_size,
                              hipStream_t stream) {
    const int T = 128;
    const int n = in_sizes[0] / T;        // 100000
    const int E = in_sizes[1] / 2;        // 600000

    const float* x   = (const float*)d_in[0];
    const int* eidx  = (const int*)d_in[1];
    const int* row   = eidx;
    const int* col   = eidx + E;
    const float* We1 = (const float*)d_in[2];
    const float* be1 = (const float*)d_in[3];
    const float* We2 = (const float*)d_in[4];
    const float* be2 = (const float*)d_in[5];
    const float* We3 = (const float*)d_in[6];
    const float* be3 = (const float*)d_in[7];
    const float* Wd1 = (const float*)d_in[8];
    const float* bd1 = (const float*)d_in[9];
    const float* Wd2 = (const float*)d_in[10];
    const float* bd2 = (const float*)d_in[11];
    const float* Wd3 = (const float*)d_in[12];
    const float* bd3 = (const float*)d_in[13];
    float* out = (float*)d_out;

    // workspace layout (all 16B aligned)
    char* base = (char*)d_ws;
    int*   deg    = (int*)base;   base += (size_t)n * 4;
    int*   offs   = (int*)base;   base += (size_t)(n + 4) * 4;
    int*   cursor = (int*)base;   base += (size_t)(n + 4) * 4;
    int*   bsum   = (int*)base;   base += (size_t)1024 * 4;
    float* dinv_s = (float*)base; base += (size_t)n * 4;
    float* dinv_h = (float*)base; base += (size_t)n * 4;
    int*   src    = (int*)base;   base += (size_t)E * 4;
    float* bufA   = (float*)base; base += (size_t)n * 64 * 4;
    float* bufB   = (float*)base; base += (size_t)n * 64 * 4;
    (void)ws_size;

    const int BLK = 256;
    const int nb = ceil_div(n + 1, SCAN_BLK);   // scan covers [0, n]

    // --- degrees & norms ---
    hipMemsetAsync(deg, 0, (size_t)n * 4, stream);
    deg_kernel<<<ceil_div(E, BLK), BLK, 0, stream>>>(col, deg, E);
    dinv_kernel<<<ceil_div(n, BLK), BLK, 0, stream>>>(deg, dinv_s, dinv_h, n);

    // --- CSR build ---
    blk_reduce_kernel<<<nb, SCAN_BLK, 0, stream>>>(deg, bsum, n);
    bsum_scan_kernel<<<1, 1024, 0, stream>>>(bsum, nb);
    offs_kernel<<<nb, SCAN_BLK, 0, stream>>>(deg, bsum, offs, n);
    hipMemcpyAsync(cursor, offs, (size_t)n * 4, hipMemcpyDeviceToDevice, stream);
    csr_fill_kernel<<<ceil_div(E, BLK), BLK, 0, stream>>>(row, col, cursor, src, E);

    const int gblocks = ceil_div(n, 4);   // 4 waves (nodes) per 256-thread block

    // ================= encoder (smooth): GEMM(scale dinv_s) then gather =================
    // L1: u1 = dinv_s ⊙ (x @ We1); a1 = dinv_s[c](Σu1 + u1[c]) + be1
    gemm_tile<128, 64, 4, false, false, false, true><<<ceil_div(n, 64), BLK, 0, stream>>>(
        x, We1, nullptr, dinv_s, bufA, n);
    gather_wave<64, false, false, true, false><<<gblocks, BLK, 0, stream>>>(
        bufA, offs, src, dinv_s, nullptr, be1, bufB, n);

    // L2: u2 = dinv_s ⊙ (relu(a1) @ We2); a2 = dinv_s[c](Σu2 + u2[c]) + be2
    gemm_tile<64, 32, 4, true, false, false, true><<<ceil_div(n, 128), BLK, 0, stream>>>(
        bufB, We2, nullptr, dinv_s, bufA, n);
    gather_wave<32, false, false, true, false><<<gblocks, BLK, 0, stream>>>(
        bufA, offs, src, dinv_s, nullptr, be2, bufB, n);

    // L3: u3 = dinv_s ⊙ (relu(a2) @ We3); Z' = dinv_h ⊙ (dinv_s[c](Σu3+u3[c]) + be3)
    gemm_tile<32, 16, 4, true, false, false, true><<<ceil_div(n, 256), BLK, 0, stream>>>(
        bufB, We3, nullptr, dinv_s, bufA, n);
    gather_wave<16, false, false, true, true><<<gblocks, BLK, 0, stream>>>(
        bufA, offs, src, dinv_s, dinv_h, be3, bufB, n);

    // ================= decoder (sharp): gather then GEMM(scale dinv_h) =================
    // L4: P = dinv_h[c](2 relu(Z'[c]) - Σ relu(Z'[src])); u4 = dinv_h ⊙ relu(P@Wd1+bd1)
    gather_wave<16, true, true, false, false><<<gblocks, BLK, 0, stream>>>(
        bufB, offs, src, dinv_h, nullptr, nullptr, bufA, n);
    gemm_tile<16, 32, 4, false, true, true, true><<<ceil_div(n, 128), BLK, 0, stream>>>(
        bufA, Wd1, bd1, dinv_h, bufB, n);

    // L5: P = dinv_h[c](2 u4[c] - Σ u4); u5 = dinv_h ⊙ relu(P@Wd2+bd2)
    gather_wave<32, false, true, false, false><<<gblocks, BLK, 0, stream>>>(
        bufB, offs, src, dinv_h, nullptr, nullptr, bufA, n);
    gemm_tile<32, 64, 4, false, true, true, true><<<ceil_div(n, 64), BLK, 0, stream>>>(
        bufA, Wd2, bd2, dinv_h, bufB, n);

    // L6: P = dinv_h[c](2 u5[c] - Σ u5); out = P @ Wd3 + bd3
    gather_wave<64, false, true, false, false><<<gblocks, BLK, 0, stream>>>(
        bufB, offs, src, dinv_h, nullptr, nullptr, bufA, n);
    gemm_tile<64, 128, 4, false, true, false, false><<<ceil_div(n, 32), BLK, 0, stream>>>(
        bufA, Wd3, bd3, nullptr, out, n);
}

// Round 6
// 384.465 us; speedup vs baseline: 2.0266x; 1.0668x over previous
//
#include <hip/hip_runtime.h>

// GALA graph autoencoder on MI355X — round 6: degree-relabeled pipeline.
// Counting-sort nodes by in-degree (block-aggregated, no contended atomics), then run
// EVERYTHING in permuted slot space: CSR, dinv vectors, intermediate buffers. Gathers
// are plain thread-per-(slot,d4) — coalesced, no indirection — with zero intra-wave
// trip divergence (degrees monotone in slot). Permutation applied only at L1 GEMM
// input staging (x[order[row]]) and L6 GEMM output write (out[order[row]]).
// Weightless algebra: prop = dinv ⊙ (A^T (dinv ⊙ h)) with self-loop folded.

static inline int ceil_div(int a, int b) { return (a + b - 1) / b; }

#define SCAN_BLK 256
#define NBINS 64

// ---------------- degree ----------------

__global__ void deg_kernel(const int* __restrict__ col, int* __restrict__ deg, int E) {
    int e = blockIdx.x * blockDim.x + threadIdx.x;
    if (e < E) atomicAdd(&deg[col[e]], 1);
}

// ---------------- counting sort by degree (deterministic, block-aggregated) ----------------

// per-block LDS histogram -> blockhist[block*NBINS + bin]
__global__ void hist_kernel(const int* __restrict__ deg, int* __restrict__ blockhist, int n) {
    __shared__ int lh[NBINS];
    if (threadIdx.x < NBINS) lh[threadIdx.x] = 0;
    __syncthreads();
    int i = blockIdx.x * SCAN_BLK + threadIdx.x;
    if (i < n) {
        int d = deg[i]; if (d >= NBINS) d = NBINS - 1;
        atomicAdd(&lh[d], 1);                       // LDS atomic, block-local
    }
    __syncthreads();
    if (threadIdx.x < NBINS) blockhist[blockIdx.x * NBINS + threadIdx.x] = lh[threadIdx.x];
}

// one block per bin (64 blocks, 512 threads): exclusive-scan blockhist[:,bin] over
// blocks (in place) and emit bintot[bin]. Requires nb <= 512.
__global__ void binscan_kernel(int* __restrict__ blockhist, int* __restrict__ bintot, int nb) {
    __shared__ int s[512];
    int bin = blockIdx.x, t = threadIdx.x;
    int v = (t < nb) ? blockhist[t * NBINS + bin] : 0;
    s[t] = v;
    __syncthreads();
    for (int st = 1; st < 512; st <<= 1) {
        int a = (t >= st) ? s[t - st] : 0;
        __syncthreads();
        s[t] += a;
        __syncthreads();
    }
    if (t < nb) blockhist[t * NBINS + bin] = s[t] - v;   // exclusive over blocks
    if (t == 0) bintot[bin] = s[511];                    // total (zero-padded tail)
}

// 1 block, 64 threads: exclusive scan of bintot -> binbase
__global__ void base_scan_kernel(const int* __restrict__ bintot, int* __restrict__ binbase) {
    __shared__ int s[NBINS];
    int t = threadIdx.x;
    int v = bintot[t];
    s[t] = v;
    __syncthreads();
    for (int st = 1; st < NBINS; st <<= 1) {
        int a = (t >= st) ? s[t - st] : 0;
        __syncthreads();
        s[t] += a;
        __syncthreads();
    }
    binbase[t] = s[t] - v;
}

// placement: slot = binbase[bin] + blockexcl[block][bin] + rank-in-block
__global__ void place_kernel(const int* __restrict__ deg, const int* __restrict__ blockhist,
                             const int* __restrict__ binbase, int* __restrict__ order,
                             int* __restrict__ slotof, int n) {
    __shared__ int lh[NBINS];
    if (threadIdx.x < NBINS) lh[threadIdx.x] = 0;
    __syncthreads();
    int i = blockIdx.x * SCAN_BLK + threadIdx.x;
    if (i < n) {
        int d = deg[i]; if (d >= NBINS) d = NBINS - 1;
        int r = atomicAdd(&lh[d], 1);               // LDS atomic, block-local
        int slot = binbase[d] + blockhist[blockIdx.x * NBINS + d] + r;
        order[slot] = i;
        slotof[i] = slot;
    }
}

// permuted degree + dinv vectors in slot space
__global__ void dinvp_kernel(const int* __restrict__ deg, const int* __restrict__ order,
                             int* __restrict__ degp, float* __restrict__ dinv_s,
                             float* __restrict__ dinv_h, int n) {
    int s = blockIdx.x * blockDim.x + threadIdx.x;
    if (s < n) {
        float d = (float)deg[order[s]];
        degp[s] = deg[order[s]];
        dinv_s[s] = rsqrtf(d + 1.0f);   // smooth: indeg + 1
        dinv_h[s] = rsqrtf(d + 2.0f);   // sharp:  indeg + 2
    }
}

// ---------------- CSR build (slot space): block scan of degp ----------------

__global__ void blk_reduce_kernel(const int* __restrict__ deg, int* __restrict__ bsum, int n) {
    __shared__ int s[SCAN_BLK];
    int i = blockIdx.x * SCAN_BLK + threadIdx.x;
    s[threadIdx.x] = (i < n) ? deg[i] : 0;
    __syncthreads();
    for (int st = SCAN_BLK / 2; st > 0; st >>= 1) {
        if (threadIdx.x < st) s[threadIdx.x] += s[threadIdx.x + st];
        __syncthreads();
    }
    if (threadIdx.x == 0) bsum[blockIdx.x] = s[0];
}

__global__ void bsum_scan_kernel(int* bsum, int nb) {
    __shared__ int s[1024];
    int t = threadIdx.x;
    int v0 = (t < nb) ? bsum[t] : 0;
    s[t] = v0;
    __syncthreads();
    for (int st = 1; st < 1024; st <<= 1) {
        int add = (t >= st) ? s[t - st] : 0;
        __syncthreads();
        s[t] += add;
        __syncthreads();
    }
    if (t < nb) bsum[t] = s[t] - v0;  // exclusive
}

__global__ void offs_kernel(const int* __restrict__ deg, const int* __restrict__ bpre,
                            int* __restrict__ offs, int n) {
    __shared__ int s[SCAN_BLK];
    int i = blockIdx.x * SCAN_BLK + threadIdx.x;
    int t = threadIdx.x;
    int v0 = (i < n) ? deg[i] : 0;
    s[t] = v0;
    __syncthreads();
    for (int st = 1; st < SCAN_BLK; st <<= 1) {
        int add = (t >= st) ? s[t - st] : 0;
        __syncthreads();
        s[t] += add;
        __syncthreads();
    }
    if (i <= n) offs[i] = bpre[blockIdx.x] + s[t] - v0;
}

// fill CSR with slot-space src ids, keyed by slot-space col
__global__ void csr_fill_kernel(const int* __restrict__ row, const int* __restrict__ col,
                                const int* __restrict__ slotof, int* __restrict__ cursor,
                                int* __restrict__ src, int E) {
    int e = blockIdx.x * blockDim.x + threadIdx.x;
    if (e >= E) return;
    int cs = slotof[col[e]];
    int p = atomicAdd(&cursor[cs], 1);
    src[p] = slotof[row[e]];
}

// ---------------- register-blocked GEMM ----------------
// out[n,DOUT] = (f(A[inperm]) @ W (+bias) (relu)) * (rs[row]?), written to out[outperm]

template <int DIN, int DOUT, int RPT, bool RELU_IN, bool ADD_BIAS, bool RELU_OUT,
          bool SCALE_ROW, bool IN_PERM, bool OUT_PERM>
__global__ __launch_bounds__(256) void gemm_tile(const float* __restrict__ A,
                                                 const float* __restrict__ W,
                                                 const float* __restrict__ bias,
                                                 const float* __restrict__ rs,
                                                 const int* __restrict__ map,
                                                 float* __restrict__ out, int n) {
    constexpr int CG  = DOUT / 4;     // col groups of 4
    constexpr int RPI = 256 / CG;     // row stride between a thread's rows
    constexpr int BM  = RPI * RPT;    // rows per block
    constexpr int LD  = DIN + 4;      // padded LDS stride
    constexpr int Q   = DIN / 4;      // float4 per row
    __shared__ float As[BM * LD];

    const int row0 = blockIdx.x * BM;
    for (int i = threadIdx.x; i < BM * Q; i += 256) {
        int r = i / Q, j = i % Q;
        float4 v = make_float4(0.f, 0.f, 0.f, 0.f);
        int gr = row0 + r;
        if (gr < n) {
            int arow = IN_PERM ? map[gr] : gr;
            v = *(const float4*)(A + (size_t)arow * DIN + j * 4);
        }
        if (RELU_IN) {
            v.x = fmaxf(v.x, 0.f); v.y = fmaxf(v.y, 0.f);
            v.z = fmaxf(v.z, 0.f); v.w = fmaxf(v.w, 0.f);
        }
        *(float4*)(&As[r * LD + j * 4]) = v;
    }
    __syncthreads();

    const int cgid = threadIdx.x % CG;
    const int rsub = threadIdx.x / CG;
    float4 acc[RPT];
#pragma unroll
    for (int rr = 0; rr < RPT; ++rr) acc[rr] = make_float4(0.f, 0.f, 0.f, 0.f);

#pragma unroll 4
    for (int k4 = 0; k4 < Q; ++k4) {
        const float4* wp = (const float4*)(W + (size_t)k4 * 4 * DOUT) + cgid;
        float4 w0 = wp[0];
        float4 w1 = wp[CG];
        float4 w2 = wp[2 * CG];
        float4 w3 = wp[3 * CG];
#pragma unroll
        for (int rr = 0; rr < RPT; ++rr) {
            float4 a = *(const float4*)(&As[(rsub + rr * RPI) * LD + k4 * 4]);
            acc[rr].x = fmaf(a.x, w0.x, fmaf(a.y, w1.x, fmaf(a.z, w2.x, fmaf(a.w, w3.x, acc[rr].x))));
            acc[rr].y = fmaf(a.x, w0.y, fmaf(a.y, w1.y, fmaf(a.z, w2.y, fmaf(a.w, w3.y, acc[rr].y))));
            acc[rr].z = fmaf(a.x, w0.z, fmaf(a.y, w1.z, fmaf(a.z, w2.z, fmaf(a.w, w3.z, acc[rr].z))));
            acc[rr].w = fmaf(a.x, w0.w, fmaf(a.y, w1.w, fmaf(a.z, w2.w, fmaf(a.w, w3.w, acc[rr].w))));
        }
    }

    float4 b4 = make_float4(0.f, 0.f, 0.f, 0.f);
    if (ADD_BIAS) b4 = *(const float4*)(bias + cgid * 4);
#pragma unroll
    for (int rr = 0; rr < RPT; ++rr) {
        int row = row0 + rsub + rr * RPI;
        if (row >= n) continue;
        float4 o = acc[rr];
        if (ADD_BIAS) { o.x += b4.x; o.y += b4.y; o.z += b4.z; o.w += b4.w; }
        if (RELU_OUT) {
            o.x = fmaxf(o.x, 0.f); o.y = fmaxf(o.y, 0.f);
            o.z = fmaxf(o.z, 0.f); o.w = fmaxf(o.w, 0.f);
        }
        if (SCALE_ROW) {
            float sc = rs[row];
            o.x *= sc; o.y *= sc; o.z *= sc; o.w *= sc;
        }
        int orow = OUT_PERM ? map[row] : row;
        *(float4*)(out + (size_t)orow * DOUT + cgid * 4) = o;
    }
}

// ---------------- propagation: thread-per-(slot,d4) CSR gather ----------------
// All arrays in slot space; degrees monotone in slot -> no intra-wave divergence.
//   S = sum_e f(u[src[e]]),  self = f(u[c])
//   smooth: t = dinv[c]*(S + self) (+bias);  sharp: t = dinv[c]*(2*self - S) (+bias)
//   optional post-scale by ps[c].

template <int DOUT, bool RELU_IN, bool SHARP, bool ADD_BIAS, bool POST_SCALE>
__global__ __launch_bounds__(256) void gather_tpd(
        const float* __restrict__ u, const int* __restrict__ offs,
        const int* __restrict__ src, const float* __restrict__ dinv,
        const float* __restrict__ ps, const float* __restrict__ bias,
        float* __restrict__ out, int n) {
    constexpr int DQ = DOUT / 4;
    constexpr int SH = (DOUT == 64) ? 4 : (DOUT == 32) ? 3 : 2;
    int idx = blockIdx.x * blockDim.x + threadIdx.x;
    int node = idx >> SH;
    if (node >= n) return;
    int d4 = (idx & (DQ - 1)) << 2;

    float4 self4 = *(const float4*)(u + (size_t)node * DOUT + d4);
    if (RELU_IN) {
        self4.x = fmaxf(self4.x, 0.f); self4.y = fmaxf(self4.y, 0.f);
        self4.z = fmaxf(self4.z, 0.f); self4.w = fmaxf(self4.w, 0.f);
    }
    float4 acc = make_float4(0.f, 0.f, 0.f, 0.f);
    int s = offs[node], e1 = offs[node + 1];
    for (int e = s; e < e1; ++e) {
        int r = src[e];
        float4 v = *(const float4*)(u + (size_t)r * DOUT + d4);
        if (RELU_IN) {
            v.x = fmaxf(v.x, 0.f); v.y = fmaxf(v.y, 0.f);
            v.z = fmaxf(v.z, 0.f); v.w = fmaxf(v.w, 0.f);
        }
        acc.x += v.x; acc.y += v.y; acc.z += v.z; acc.w += v.w;
    }
    float dv = dinv[node];
    float4 t;
    if (SHARP) {
        t.x = dv * (2.f * self4.x - acc.x); t.y = dv * (2.f * self4.y - acc.y);
        t.z = dv * (2.f * self4.z - acc.z); t.w = dv * (2.f * self4.w - acc.w);
    } else {
        t.x = dv * (acc.x + self4.x); t.y = dv * (acc.y + self4.y);
        t.z = dv * (acc.z + self4.z); t.w = dv * (acc.w + self4.w);
    }
    if (ADD_BIAS) {
        float4 b4 = *(const float4*)(bias + d4);
        t.x += b4.x; t.y += b4.y; t.z += b4.z; t.w += b4.w;
    }
    if (POST_SCALE) {
        float p = ps[node];
        t.x *= p; t.y *= p; t.z *= p; t.w *= p;
    }
    *(float4*)(out + (size_t)node * DOUT + d4) = t;
}

// ---------------- host orchestration ----------------

extern "C" void kernel_launch(void* const* d_in, const int* in_sizes, int n_in,
                              void* d_out, int out_size, void* d_ws, size_t ws_size,
                              hipStream_t stream) {
    const int T = 128;
    const int n = in_sizes[0] / T;        // 100000
    const int E = in_sizes[1] / 2;        // 600000

    const float* x   = (const float*)d_in[0];
    const int* eidx  = (const int*)d_in[1];
    const int* row   = eidx;
    const int* col   = eidx + E;
    const float* We1 = (const float*)d_in[2];
    const float* be1 = (const float*)d_in[3];
    const float* We2 = (const float*)d_in[4];
    const float* be2 = (const float*)d_in[5];
    const float* We3 = (const float*)d_in[6];
    const float* be3 = (const float*)d_in[7];
    const float* Wd1 = (const float*)d_in[8];
    const float* bd1 = (const float*)d_in[9];
    const float* Wd2 = (const float*)d_in[10];
    const float* bd2 = (const float*)d_in[11];
    const float* Wd3 = (const float*)d_in[12];
    const float* bd3 = (const float*)d_in[13];
    float* out = (float*)d_out;

    // workspace layout (all 16B aligned)
    char* base = (char*)d_ws;
    int*   deg     = (int*)base;   base += (size_t)n * 4;
    int*   degp    = (int*)base;   base += (size_t)n * 4;
    int*   offs    = (int*)base;   base += (size_t)(n + 4) * 4;
    int*   cursor  = (int*)base;   base += (size_t)(n + 4) * 4;
    int*   bsum    = (int*)base;   base += (size_t)1024 * 4;
    int*   bhist   = (int*)base;   base += (size_t)512 * NBINS * 4;
    int*   bintot  = (int*)base;   base += (size_t)NBINS * 4;
    int*   binbase = (int*)base;   base += (size_t)NBINS * 4;
    int*   order   = (int*)base;   base += (size_t)n * 4;
    int*   slotof  = (int*)base;   base += (size_t)n * 4;
    float* dinv_s  = (float*)base; base += (size_t)n * 4;
    float* dinv_h  = (float*)base; base += (size_t)n * 4;
    int*   src     = (int*)base;   base += (size_t)E * 4;
    float* bufA    = (float*)base; base += (size_t)n * 64 * 4;
    float* bufB    = (float*)base; base += (size_t)n * 64 * 4;
    (void)ws_size;

    const int BLK = 256;
    const int nhb = ceil_div(n, SCAN_BLK);        // 391 blocks for hist/place
    const int nb  = ceil_div(n + 1, SCAN_BLK);    // scan covers [0, n]

    // --- degrees ---
    hipMemsetAsync(deg, 0, (size_t)n * 4, stream);
    deg_kernel<<<ceil_div(E, BLK), BLK, 0, stream>>>(col, deg, E);

    // --- counting sort by degree (deterministic) ---
    hist_kernel<<<nhb, SCAN_BLK, 0, stream>>>(deg, bhist, n);
    binscan_kernel<<<NBINS, 512, 0, stream>>>(bhist, bintot, nhb);
    base_scan_kernel<<<1, NBINS, 0, stream>>>(bintot, binbase);
    place_kernel<<<nhb, SCAN_BLK, 0, stream>>>(deg, bhist, binbase, order, slotof, n);
    dinvp_kernel<<<ceil_div(n, BLK), BLK, 0, stream>>>(deg, order, degp, dinv_s, dinv_h, n);

    // --- CSR build in slot space ---
    blk_reduce_kernel<<<nb, SCAN_BLK, 0, stream>>>(degp, bsum, n);
    bsum_scan_kernel<<<1, 1024, 0, stream>>>(bsum, nb);
    offs_kernel<<<nb, SCAN_BLK, 0, stream>>>(degp, bsum, offs, n);
    hipMemcpyAsync(cursor, offs, (size_t)n * 4, hipMemcpyDeviceToDevice, stream);
    csr_fill_kernel<<<ceil_div(E, BLK), BLK, 0, stream>>>(row, col, slotof, cursor, src, E);

    auto gath_grid = [&](int dout) { return ceil_div(n * (dout >> 2), BLK); };

    // ================= encoder (smooth): GEMM(scale dinv_s) then gather =================
    // L1: u1 = dinv_s ⊙ (x[order] @ We1); a1 = dinv_s[c](Σu1 + u1[c]) + be1
    gemm_tile<128, 64, 4, false, false, false, true, true, false>
        <<<ceil_div(n, 64), BLK, 0, stream>>>(x, We1, nullptr, dinv_s, order, bufA, n);
    gather_tpd<64, false, false, true, false><<<gath_grid(64), BLK, 0, stream>>>(
        bufA, offs, src, dinv_s, nullptr, be1, bufB, n);

    // L2: u2 = dinv_s ⊙ (relu(a1) @ We2); a2 = dinv_s[c](Σu2 + u2[c]) + be2
    gemm_tile<64, 32, 4, true, false, false, true, false, false>
        <<<ceil_div(n, 128), BLK, 0, stream>>>(bufB, We2, nullptr, dinv_s, nullptr, bufA, n);
    gather_tpd<32, false, false, true, false><<<gath_grid(32), BLK, 0, stream>>>(
        bufA, offs, src, dinv_s, nullptr, be2, bufB, n);

    // L3: u3 = dinv_s ⊙ (relu(a2) @ We3); Z' = dinv_h ⊙ (dinv_s[c](Σu3+u3[c]) + be3)
    gemm_tile<32, 16, 4, true, false, false, true, false, false>
        <<<ceil_div(n, 256), BLK, 0, stream>>>(bufB, We3, nullptr, dinv_s, nullptr, bufA, n);
    gather_tpd<16, false, false, true, true><<<gath_grid(16), BLK, 0, stream>>>(
        bufA, offs, src, dinv_s, dinv_h, be3, bufB, n);

    // ================= decoder (sharp): gather then GEMM(scale dinv_h) =================
    // L4: P = dinv_h[c](2 relu(Z'[c]) - Σ relu(Z'[src])); u4 = dinv_h ⊙ relu(P@Wd1+bd1)
    gather_tpd<16, true, true, false, false><<<gath_grid(16), BLK, 0, stream>>>(
        bufB, offs, src, dinv_h, nullptr, nullptr, bufA, n);
    gemm_tile<16, 32, 4, false, true, true, true, false, false>
        <<<ceil_div(n, 128), BLK, 0, stream>>>(bufA, Wd1, bd1, dinv_h, nullptr, bufB, n);

    // L5: P = dinv_h[c](2 u4[c] - Σ u4); u5 = dinv_h ⊙ relu(P@Wd2+bd2)
    gather_tpd<32, false, true, false, false><<<gath_grid(32), BLK, 0, stream>>>(
        bufB, offs, src, dinv_h, nullptr, nullptr, bufA, n);
    gemm_tile<32, 64, 4, false, true, true, true, false, false>
        <<<ceil_div(n, 64), BLK, 0, stream>>>(bufA, Wd2, bd2, dinv_h, nullptr, bufB, n);

    // L6: P = dinv_h[c](2 u5[c] - Σ u5); out[order] = P @ Wd3 + bd3
    gather_tpd<64, false, true, false, false><<<gath_grid(64), BLK, 0, stream>>>(
        bufB, offs, src, dinv_h, nullptr, nullptr, bufA, n);
    gemm_tile<64, 128, 4, false, true, false, false, false, true>
        <<<ceil_div(n, 32), BLK, 0, stream>>>(bufA, Wd3, bd3, nullptr, order, out, n);
}

// Round 7
// 378.014 us; speedup vs baseline: 2.0612x; 1.0171x over previous
//
#include <hip/hip_runtime.h>

// GALA graph autoencoder on MI355X — round 7: scalar-broadcast GEMM.
// Pipeline (unchanged from r6): degree counting-sort relabel -> slot space; CSR gather
// propagation (thread-per-(slot,d4), zero trip divergence); weightless algebra
// prop = dinv ⊙ (A^T (dinv ⊙ h)) with self-loop folded.
// NEW GEMM: lane = row, wave = contiguous 16-col strip -> W/bias fetches are
// wave-uniform => s_load via scalar cache (no VMEM in inner loop). A-tile in LDS with
// stride DIN+1 => per-k column read is 2 lanes/bank (free). 1 ds_read_b32 + WPC*4 FMA/k.

static inline int ceil_div(int a, int b) { return (a + b - 1) / b; }

#define SCAN_BLK 256
#define NBINS 64

// ---------------- degree ----------------

__global__ void deg_kernel(const int* __restrict__ col, int* __restrict__ deg, int E) {
    int e = blockIdx.x * blockDim.x + threadIdx.x;
    if (e < E) atomicAdd(&deg[col[e]], 1);
}

// ---------------- counting sort by degree (deterministic, block-aggregated) ----------------

__global__ void hist_kernel(const int* __restrict__ deg, int* __restrict__ blockhist, int n) {
    __shared__ int lh[NBINS];
    if (threadIdx.x < NBINS) lh[threadIdx.x] = 0;
    __syncthreads();
    int i = blockIdx.x * SCAN_BLK + threadIdx.x;
    if (i < n) {
        int d = deg[i]; if (d >= NBINS) d = NBINS - 1;
        atomicAdd(&lh[d], 1);                       // LDS atomic, block-local
    }
    __syncthreads();
    if (threadIdx.x < NBINS) blockhist[blockIdx.x * NBINS + threadIdx.x] = lh[threadIdx.x];
}

// one block per bin: exclusive-scan blockhist[:,bin] over blocks; emit bintot[bin]
__global__ void binscan_kernel(int* __restrict__ blockhist, int* __restrict__ bintot, int nb) {
    __shared__ int s[512];
    int bin = blockIdx.x, t = threadIdx.x;
    int v = (t < nb) ? blockhist[t * NBINS + bin] : 0;
    s[t] = v;
    __syncthreads();
    for (int st = 1; st < 512; st <<= 1) {
        int a = (t >= st) ? s[t - st] : 0;
        __syncthreads();
        s[t] += a;
        __syncthreads();
    }
    if (t < nb) blockhist[t * NBINS + bin] = s[t] - v;   // exclusive over blocks
    if (t == 0) bintot[bin] = s[511];
}

__global__ void base_scan_kernel(const int* __restrict__ bintot, int* __restrict__ binbase) {
    __shared__ int s[NBINS];
    int t = threadIdx.x;
    int v = bintot[t];
    s[t] = v;
    __syncthreads();
    for (int st = 1; st < NBINS; st <<= 1) {
        int a = (t >= st) ? s[t - st] : 0;
        __syncthreads();
        s[t] += a;
        __syncthreads();
    }
    binbase[t] = s[t] - v;
}

__global__ void place_kernel(const int* __restrict__ deg, const int* __restrict__ blockhist,
                             const int* __restrict__ binbase, int* __restrict__ order,
                             int* __restrict__ slotof, int n) {
    __shared__ int lh[NBINS];
    if (threadIdx.x < NBINS) lh[threadIdx.x] = 0;
    __syncthreads();
    int i = blockIdx.x * SCAN_BLK + threadIdx.x;
    if (i < n) {
        int d = deg[i]; if (d >= NBINS) d = NBINS - 1;
        int r = atomicAdd(&lh[d], 1);               // LDS atomic, block-local
        int slot = binbase[d] + blockhist[blockIdx.x * NBINS + d] + r;
        order[slot] = i;
        slotof[i] = slot;
    }
}

__global__ void dinvp_kernel(const int* __restrict__ deg, const int* __restrict__ order,
                             int* __restrict__ degp, float* __restrict__ dinv_s,
                             float* __restrict__ dinv_h, int n) {
    int s = blockIdx.x * blockDim.x + threadIdx.x;
    if (s < n) {
        int dd = deg[order[s]];
        float d = (float)dd;
        degp[s] = dd;
        dinv_s[s] = rsqrtf(d + 1.0f);   // smooth: indeg + 1
        dinv_h[s] = rsqrtf(d + 2.0f);   // sharp:  indeg + 2
    }
}

// ---------------- CSR build (slot space) ----------------

__global__ void blk_reduce_kernel(const int* __restrict__ deg, int* __restrict__ bsum, int n) {
    __shared__ int s[SCAN_BLK];
    int i = blockIdx.x * SCAN_BLK + threadIdx.x;
    s[threadIdx.x] = (i < n) ? deg[i] : 0;
    __syncthreads();
    for (int st = SCAN_BLK / 2; st > 0; st >>= 1) {
        if (threadIdx.x < st) s[threadIdx.x] += s[threadIdx.x + st];
        __syncthreads();
    }
    if (threadIdx.x == 0) bsum[blockIdx.x] = s[0];
}

__global__ void bsum_scan_kernel(int* bsum, int nb) {
    __shared__ int s[1024];
    int t = threadIdx.x;
    int v0 = (t < nb) ? bsum[t] : 0;
    s[t] = v0;
    __syncthreads();
    for (int st = 1; st < 1024; st <<= 1) {
        int add = (t >= st) ? s[t - st] : 0;
        __syncthreads();
        s[t] += add;
        __syncthreads();
    }
    if (t < nb) bsum[t] = s[t] - v0;  // exclusive
}

__global__ void offs_kernel(const int* __restrict__ deg, const int* __restrict__ bpre,
                            int* __restrict__ offs, int n) {
    __shared__ int s[SCAN_BLK];
    int i = blockIdx.x * SCAN_BLK + threadIdx.x;
    int t = threadIdx.x;
    int v0 = (i < n) ? deg[i] : 0;
    s[t] = v0;
    __syncthreads();
    for (int st = 1; st < SCAN_BLK; st <<= 1) {
        int add = (t >= st) ? s[t - st] : 0;
        __syncthreads();
        s[t] += add;
        __syncthreads();
    }
    if (i <= n) offs[i] = bpre[blockIdx.x] + s[t] - v0;
}

__global__ void csr_fill_kernel(const int* __restrict__ row, const int* __restrict__ col,
                                const int* __restrict__ slotof, int* __restrict__ cursor,
                                int* __restrict__ src, int E) {
    int e = blockIdx.x * blockDim.x + threadIdx.x;
    if (e >= E) return;
    int cs = slotof[col[e]];
    int p = atomicAdd(&cursor[cs], 1);
    src[p] = slotof[row[e]];
}

// ---------------- scalar-broadcast GEMM ----------------
// out[n,DOUT] = (f(A[inperm]) @ W (+bias) (relu)) * (rs[row]?), written to out[outperm]
// 256 threads = 4 waves; block owns 64 rows (lane = row); wave w owns cols
// [w*DOUT/4, (w+1)*DOUT/4). W/bias addresses wave-uniform -> scalar loads.

template <int DIN, int DOUT, bool RELU_IN, bool ADD_BIAS, bool RELU_OUT,
          bool SCALE_ROW, bool IN_PERM, bool OUT_PERM>
__global__ __launch_bounds__(256) void gemm_wave(const float* __restrict__ A,
                                                 const float* __restrict__ W,
                                                 const float* __restrict__ bias,
                                                 const float* __restrict__ rs,
                                                 const int* __restrict__ map,
                                                 float* __restrict__ out, int n) {
    constexpr int WPC = DOUT / 16;    // float4 col-groups per wave
    constexpr int LD  = DIN + 1;      // odd stride: column read = 2 lanes/bank (free)
    constexpr int Q   = DIN / 4;
    __shared__ float As[64 * LD];

    const int row0 = blockIdx.x * 64;
    const int lane = threadIdx.x & 63;
    const int wave = __builtin_amdgcn_readfirstlane((int)(threadIdx.x >> 6));

    // stage 64 x DIN A-tile (relu + optional row permutation fused)
    for (int i = threadIdx.x; i < 64 * Q; i += 256) {
        int r = i / Q, j4 = i % Q;
        int gr = row0 + r;
        float4 v = make_float4(0.f, 0.f, 0.f, 0.f);
        if (gr < n) {
            int ar = IN_PERM ? map[gr] : gr;
            v = *(const float4*)(A + (size_t)ar * DIN + j4 * 4);
        }
        if (RELU_IN) {
            v.x = fmaxf(v.x, 0.f); v.y = fmaxf(v.y, 0.f);
            v.z = fmaxf(v.z, 0.f); v.w = fmaxf(v.w, 0.f);
        }
        float* p = &As[r * LD + j4 * 4];
        p[0] = v.x; p[1] = v.y; p[2] = v.z; p[3] = v.w;
    }
    __syncthreads();

    float4 acc[WPC];
#pragma unroll
    for (int j = 0; j < WPC; ++j) acc[j] = make_float4(0.f, 0.f, 0.f, 0.f);

    const float* Wb = W + wave * (WPC * 4);   // wave-uniform base
#pragma unroll 4
    for (int k = 0; k < DIN; ++k) {
        float a = As[lane * LD + k];
#pragma unroll
        for (int j = 0; j < WPC; ++j) {
            float4 w = *(const float4*)(Wb + (size_t)k * DOUT + j * 4);  // scalar load
            acc[j].x = fmaf(a, w.x, acc[j].x);
            acc[j].y = fmaf(a, w.y, acc[j].y);
            acc[j].z = fmaf(a, w.z, acc[j].z);
            acc[j].w = fmaf(a, w.w, acc[j].w);
        }
    }

    const int row = row0 + lane;
    if (row >= n) return;
    float sc = SCALE_ROW ? rs[row] : 1.0f;
    const int orow = OUT_PERM ? map[row] : row;
    float* ob = out + (size_t)orow * DOUT + wave * (WPC * 4);
#pragma unroll
    for (int j = 0; j < WPC; ++j) {
        float4 o = acc[j];
        if (ADD_BIAS) {
            const float* bb = bias + wave * (WPC * 4) + j * 4;  // scalar load
            o.x += bb[0]; o.y += bb[1]; o.z += bb[2]; o.w += bb[3];
        }
        if (RELU_OUT) {
            o.x = fmaxf(o.x, 0.f); o.y = fmaxf(o.y, 0.f);
            o.z = fmaxf(o.z, 0.f); o.w = fmaxf(o.w, 0.f);
        }
        if (SCALE_ROW) { o.x *= sc; o.y *= sc; o.z *= sc; o.w *= sc; }
        *(float4*)(ob + j * 4) = o;
    }
}

// ---------------- propagation: thread-per-(slot,d4) CSR gather ----------------

template <int DOUT, bool RELU_IN, bool SHARP, bool ADD_BIAS, bool POST_SCALE>
__global__ __launch_bounds__(256) void gather_tpd(
        const float* __restrict__ u, const int* __restrict__ offs,
        const int* __restrict__ src, const float* __restrict__ dinv,
        const float* __restrict__ ps, const float* __restrict__ bias,
        float* __restrict__ out, int n) {
    constexpr int DQ = DOUT / 4;
    constexpr int SH = (DOUT == 64) ? 4 : (DOUT == 32) ? 3 : 2;
    int idx = blockIdx.x * blockDim.x + threadIdx.x;
    int node = idx >> SH;
    if (node >= n) return;
    int d4 = (idx & (DQ - 1)) << 2;

    float4 self4 = *(const float4*)(u + (size_t)node * DOUT + d4);
    if (RELU_IN) {
        self4.x = fmaxf(self4.x, 0.f); self4.y = fmaxf(self4.y, 0.f);
        self4.z = fmaxf(self4.z, 0.f); self4.w = fmaxf(self4.w, 0.f);
    }
    float4 acc = make_float4(0.f, 0.f, 0.f, 0.f);
    int s = offs[node], e1 = offs[node + 1];
    for (int e = s; e < e1; ++e) {
        int r = src[e];
        float4 v = *(const float4*)(u + (size_t)r * DOUT + d4);
        if (RELU_IN) {
            v.x = fmaxf(v.x, 0.f); v.y = fmaxf(v.y, 0.f);
            v.z = fmaxf(v.z, 0.f); v.w = fmaxf(v.w, 0.f);
        }
        acc.x += v.x; acc.y += v.y; acc.z += v.z; acc.w += v.w;
    }
    float dv = dinv[node];
    float4 t;
    if (SHARP) {
        t.x = dv * (2.f * self4.x - acc.x); t.y = dv * (2.f * self4.y - acc.y);
        t.z = dv * (2.f * self4.z - acc.z); t.w = dv * (2.f * self4.w - acc.w);
    } else {
        t.x = dv * (acc.x + self4.x); t.y = dv * (acc.y + self4.y);
        t.z = dv * (acc.z + self4.z); t.w = dv * (acc.w + self4.w);
    }
    if (ADD_BIAS) {
        float4 b4 = *(const float4*)(bias + d4);
        t.x += b4.x; t.y += b4.y; t.z += b4.z; t.w += b4.w;
    }
    if (POST_SCALE) {
        float p = ps[node];
        t.x *= p; t.y *= p; t.z *= p; t.w *= p;
    }
    *(float4*)(out + (size_t)node * DOUT + d4) = t;
}

// ---------------- host orchestration ----------------

extern "C" void kernel_launch(void* const* d_in, const int* in_sizes, int n_in,
                              void* d_out, int out_size, void* d_ws, size_t ws_size,
                              hipStream_t stream) {
    const int T = 128;
    const int n = in_sizes[0] / T;        // 100000
    const int E = in_sizes[1] / 2;        // 600000

    const float* x   = (const float*)d_in[0];
    const int* eidx  = (const int*)d_in[1];
    const int* row   = eidx;
    const int* col   = eidx + E;
    const float* We1 = (const float*)d_in[2];
    const float* be1 = (const float*)d_in[3];
    const float* We2 = (const float*)d_in[4];
    const float* be2 = (const float*)d_in[5];
    const float* We3 = (const float*)d_in[6];
    const float* be3 = (const float*)d_in[7];
    const float* Wd1 = (const float*)d_in[8];
    const float* bd1 = (const float*)d_in[9];
    const float* Wd2 = (const float*)d_in[10];
    const float* bd2 = (const float*)d_in[11];
    const float* Wd3 = (const float*)d_in[12];
    const float* bd3 = (const float*)d_in[13];
    float* out = (float*)d_out;

    // workspace layout (all 16B aligned)
    char* base = (char*)d_ws;
    int*   deg     = (int*)base;   base += (size_t)n * 4;
    int*   degp    = (int*)base;   base += (size_t)n * 4;
    int*   offs    = (int*)base;   base += (size_t)(n + 4) * 4;
    int*   cursor  = (int*)base;   base += (size_t)(n + 4) * 4;
    int*   bsum    = (int*)base;   base += (size_t)1024 * 4;
    int*   bhist   = (int*)base;   base += (size_t)512 * NBINS * 4;
    int*   bintot  = (int*)base;   base += (size_t)NBINS * 4;
    int*   binbase = (int*)base;   base += (size_t)NBINS * 4;
    int*   order   = (int*)base;   base += (size_t)n * 4;
    int*   slotof  = (int*)base;   base += (size_t)n * 4;
    float* dinv_s  = (float*)base; base += (size_t)n * 4;
    float* dinv_h  = (float*)base; base += (size_t)n * 4;
    int*   src     = (int*)base;   base += (size_t)E * 4;
    float* bufA    = (float*)base; base += (size_t)n * 64 * 4;
    float* bufB    = (float*)base; base += (size_t)n * 64 * 4;
    (void)ws_size;

    const int BLK = 256;
    const int nhb = ceil_div(n, SCAN_BLK);
    const int nb  = ceil_div(n + 1, SCAN_BLK);

    // --- degrees ---
    hipMemsetAsync(deg, 0, (size_t)n * 4, stream);
    deg_kernel<<<ceil_div(E, BLK), BLK, 0, stream>>>(col, deg, E);

    // --- counting sort by degree ---
    hist_kernel<<<nhb, SCAN_BLK, 0, stream>>>(deg, bhist, n);
    binscan_kernel<<<NBINS, 512, 0, stream>>>(bhist, bintot, nhb);
    base_scan_kernel<<<1, NBINS, 0, stream>>>(bintot, binbase);
    place_kernel<<<nhb, SCAN_BLK, 0, stream>>>(deg, bhist, binbase, order, slotof, n);
    dinvp_kernel<<<ceil_div(n, BLK), BLK, 0, stream>>>(deg, order, degp, dinv_s, dinv_h, n);

    // --- CSR build in slot space ---
    blk_reduce_kernel<<<nb, SCAN_BLK, 0, stream>>>(degp, bsum, n);
    bsum_scan_kernel<<<1, 1024, 0, stream>>>(bsum, nb);
    offs_kernel<<<nb, SCAN_BLK, 0, stream>>>(degp, bsum, offs, n);
    hipMemcpyAsync(cursor, offs, (size_t)n * 4, hipMemcpyDeviceToDevice, stream);
    csr_fill_kernel<<<ceil_div(E, BLK), BLK, 0, stream>>>(row, col, slotof, cursor, src, E);

    auto gath_grid = [&](int dout) { return ceil_div(n * (dout >> 2), BLK); };
    const int ggrid = ceil_div(n, 64);

    // ================= encoder (smooth): GEMM(scale dinv_s) then gather =================
    // L1: u1 = dinv_s ⊙ (x[order] @ We1); a1 = dinv_s[c](Σu1 + u1[c]) + be1
    gemm_wave<128, 64, false, false, false, true, true, false>
        <<<ggrid, BLK, 0, stream>>>(x, We1, nullptr, dinv_s, order, bufA, n);
    gather_tpd<64, false, false, true, false><<<gath_grid(64), BLK, 0, stream>>>(
        bufA, offs, src, dinv_s, nullptr, be1, bufB, n);

    // L2: u2 = dinv_s ⊙ (relu(a1) @ We2); a2 = dinv_s[c](Σu2 + u2[c]) + be2
    gemm_wave<64, 32, true, false, false, true, false, false>
        <<<ggrid, BLK, 0, stream>>>(bufB, We2, nullptr, dinv_s, nullptr, bufA, n);
    gather_tpd<32, false, false, true, false><<<gath_grid(32), BLK, 0, stream>>>(
        bufA, offs, src, dinv_s, nullptr, be2, bufB, n);

    // L3: u3 = dinv_s ⊙ (relu(a2) @ We3); Z' = dinv_h ⊙ (dinv_s[c](Σu3+u3[c]) + be3)
    gemm_wave<32, 16, true, false, false, true, false, false>
        <<<ggrid, BLK, 0, stream>>>(bufB, We3, nullptr, dinv_s, nullptr, bufA, n);
    gather_tpd<16, false, false, true, true><<<gath_grid(16), BLK, 0, stream>>>(
        bufA, offs, src, dinv_s, dinv_h, be3, bufB, n);

    // ================= decoder (sharp): gather then GEMM(scale dinv_h) =================
    // L4: P = dinv_h[c](2 relu(Z'[c]) - Σ relu(Z'[src])); u4 = dinv_h ⊙ relu(P@Wd1+bd1)
    gather_tpd<16, true, true, false, false><<<gath_grid(16), BLK, 0, stream>>>(
        bufB, offs, src, dinv_h, nullptr, nullptr, bufA, n);
    gemm_wave<16, 32, false, true, true, true, false, false>
        <<<ggrid, BLK, 0, stream>>>(bufA, Wd1, bd1, dinv_h, nullptr, bufB, n);

    // L5: P = dinv_h[c](2 u4[c] - Σ u4); u5 = dinv_h ⊙ relu(P@Wd2+bd2)
    gather_tpd<32, false, true, false, false><<<gath_grid(32), BLK, 0, stream>>>(
        bufB, offs, src, dinv_h, nullptr, nullptr, bufA, n);
    gemm_wave<32, 64, false, true, true, true, false, false>
        <<<ggrid, BLK, 0, stream>>>(bufA, Wd2, bd2, dinv_h, nullptr, bufB, n);

    // L6: P = dinv_h[c](2 u5[c] - Σ u5); out[order] = P @ Wd3 + bd3
    gather_tpd<64, false, true, false, false><<<gath_grid(64), BLK, 0, stream>>>(
        bufB, offs, src, dinv_h, nullptr, nullptr, bufA, n);
    gemm_wave<64, 128, false, true, false, false, false, true>
        <<<ggrid, BLK, 0, stream>>>(bufA, Wd3, bd3, nullptr, order, out, n);
}

// Round 8
// 358.016 us; speedup vs baseline: 2.1763x; 1.0559x over previous
//
#include <hip/hip_runtime.h>

// GALA graph autoencoder on MI355X — round 8: split-bf16 MFMA GEMM (f32-accurate).
// Pipeline (r6/r7): degree counting-sort relabel -> slot space; CSR gather propagation
// (thread-per-(slot,d4), zero trip divergence); weightless algebra
// prop = dinv ⊙ (A^T (dinv ⊙ h)) with self-loop folded. Gathers unchanged (f32).
// GEMM: A split into bf16 hi+lo during LDS staging; W pre-transposed+split once per
// launch; 3 MFMA passes (hi·hi + hi·lo + lo·hi) -> ~2^-18 input error (f32-grade).
// mfma_f32_16x16x32_bf16, verified layout: A[row=l&15][k=(l>>4)*8+j], B^T same, C/D
// col=l&15,row=(l>>4)*4+r (learn_hip m89/m91).

static inline int ceil_div(int a, int b) { return (a + b - 1) / b; }

#define SCAN_BLK 256
#define NBINS 64

typedef short bf16x8 __attribute__((ext_vector_type(8)));
typedef float f32x4 __attribute__((ext_vector_type(4)));
typedef unsigned short us4 __attribute__((ext_vector_type(4)));
typedef unsigned short us8 __attribute__((ext_vector_type(8)));

__device__ __forceinline__ unsigned short bf16_rne(float x) {
    union { float f; unsigned u; } v; v.f = x;
    unsigned r = v.u + 0x7fffu + ((v.u >> 16) & 1u);
    return (unsigned short)(r >> 16);
}
__device__ __forceinline__ float bf16_f32(unsigned short h) {
    union { unsigned u; float f; } v; v.u = (unsigned)h << 16;
    return v.f;
}

// ---------------- degree ----------------

__global__ void deg_kernel(const int* __restrict__ col, int* __restrict__ deg, int E) {
    int e = blockIdx.x * blockDim.x + threadIdx.x;
    if (e < E) atomicAdd(&deg[col[e]], 1);
}

// ---------------- counting sort by degree (block-aggregated, deterministic) ----------------

__global__ void hist_kernel(const int* __restrict__ deg, int* __restrict__ blockhist, int n) {
    __shared__ int lh[NBINS];
    if (threadIdx.x < NBINS) lh[threadIdx.x] = 0;
    __syncthreads();
    int i = blockIdx.x * SCAN_BLK + threadIdx.x;
    if (i < n) {
        int d = deg[i]; if (d >= NBINS) d = NBINS - 1;
        atomicAdd(&lh[d], 1);
    }
    __syncthreads();
    if (threadIdx.x < NBINS) blockhist[blockIdx.x * NBINS + threadIdx.x] = lh[threadIdx.x];
}

__global__ void binscan_kernel(int* __restrict__ blockhist, int* __restrict__ bintot, int nb) {
    __shared__ int s[512];
    int bin = blockIdx.x, t = threadIdx.x;
    int v = (t < nb) ? blockhist[t * NBINS + bin] : 0;
    s[t] = v;
    __syncthreads();
    for (int st = 1; st < 512; st <<= 1) {
        int a = (t >= st) ? s[t - st] : 0;
        __syncthreads();
        s[t] += a;
        __syncthreads();
    }
    if (t < nb) blockhist[t * NBINS + bin] = s[t] - v;
    if (t == 0) bintot[bin] = s[511];
}

__global__ void base_scan_kernel(const int* __restrict__ bintot, int* __restrict__ binbase) {
    __shared__ int s[NBINS];
    int t = threadIdx.x;
    int v = bintot[t];
    s[t] = v;
    __syncthreads();
    for (int st = 1; st < NBINS; st <<= 1) {
        int a = (t >= st) ? s[t - st] : 0;
        __syncthreads();
        s[t] += a;
        __syncthreads();
    }
    binbase[t] = s[t] - v;
}

__global__ void place_kernel(const int* __restrict__ deg, const int* __restrict__ blockhist,
                             const int* __restrict__ binbase, int* __restrict__ order,
                             int* __restrict__ slotof, int n) {
    __shared__ int lh[NBINS];
    if (threadIdx.x < NBINS) lh[threadIdx.x] = 0;
    __syncthreads();
    int i = blockIdx.x * SCAN_BLK + threadIdx.x;
    if (i < n) {
        int d = deg[i]; if (d >= NBINS) d = NBINS - 1;
        int r = atomicAdd(&lh[d], 1);
        int slot = binbase[d] + blockhist[blockIdx.x * NBINS + d] + r;
        order[slot] = i;
        slotof[i] = slot;
    }
}

__global__ void dinvp_kernel(const int* __restrict__ deg, const int* __restrict__ order,
                             int* __restrict__ degp, float* __restrict__ dinv_s,
                             float* __restrict__ dinv_h, int n) {
    int s = blockIdx.x * blockDim.x + threadIdx.x;
    if (s < n) {
        int dd = deg[order[s]];
        float d = (float)dd;
        degp[s] = dd;
        dinv_s[s] = rsqrtf(d + 1.0f);   // smooth: indeg + 1
        dinv_h[s] = rsqrtf(d + 2.0f);   // sharp:  indeg + 2
    }
}

// ---------------- CSR build (slot space) ----------------

__global__ void blk_reduce_kernel(const int* __restrict__ deg, int* __restrict__ bsum, int n) {
    __shared__ int s[SCAN_BLK];
    int i = blockIdx.x * SCAN_BLK + threadIdx.x;
    s[threadIdx.x] = (i < n) ? deg[i] : 0;
    __syncthreads();
    for (int st = SCAN_BLK / 2; st > 0; st >>= 1) {
        if (threadIdx.x < st) s[threadIdx.x] += s[threadIdx.x + st];
        __syncthreads();
    }
    if (threadIdx.x == 0) bsum[blockIdx.x] = s[0];
}

__global__ void bsum_scan_kernel(int* bsum, int nb) {
    __shared__ int s[1024];
    int t = threadIdx.x;
    int v0 = (t < nb) ? bsum[t] : 0;
    s[t] = v0;
    __syncthreads();
    for (int st = 1; st < 1024; st <<= 1) {
        int add = (t >= st) ? s[t - st] : 0;
        __syncthreads();
        s[t] += add;
        __syncthreads();
    }
    if (t < nb) bsum[t] = s[t] - v0;  // exclusive
}

__global__ void offs_kernel(const int* __restrict__ deg, const int* __restrict__ bpre,
                            int* __restrict__ offs, int n) {
    __shared__ int s[SCAN_BLK];
    int i = blockIdx.x * SCAN_BLK + threadIdx.x;
    int t = threadIdx.x;
    int v0 = (i < n) ? deg[i] : 0;
    s[t] = v0;
    __syncthreads();
    for (int st = 1; st < SCAN_BLK; st <<= 1) {
        int add = (t >= st) ? s[t - st] : 0;
        __syncthreads();
        s[t] += add;
        __syncthreads();
    }
    if (i <= n) offs[i] = bpre[blockIdx.x] + s[t] - v0;
}

__global__ void csr_fill_kernel(const int* __restrict__ row, const int* __restrict__ col,
                                const int* __restrict__ slotof, int* __restrict__ cursor,
                                int* __restrict__ src, int E) {
    int e = blockIdx.x * blockDim.x + threadIdx.x;
    if (e >= E) return;
    int cs = slotof[col[e]];
    int p = atomicAdd(&cursor[cs], 1);
    src[p] = slotof[row[e]];
}

// ---------------- W pre-transpose + split (f32 [DIN][DOUT] -> bf16 hi/lo [DOUT][DIN]) ----------------

struct WPtrs { const float* p[6]; };

__global__ void wsplit_kernel(WPtrs wp, unsigned short* __restrict__ wt_hi,
                              unsigned short* __restrict__ wt_lo) {
    const int din[6]  = {128, 64, 32, 16, 32, 64};
    const int dout[6] = {64, 32, 16, 32, 64, 128};
    const int off[6]  = {0, 8192, 10240, 10752, 11264, 13312};
    int t = blockIdx.x * blockDim.x + threadIdx.x;
    if (t >= 21504) return;
    int l = 0;
    while (l < 5 && t >= off[l + 1]) ++l;
    int idx = t - off[l];
    int c = idx / din[l], k = idx - c * din[l];
    float a = wp.p[l][k * dout[l] + c];
    unsigned short hi = bf16_rne(a);
    unsigned short lo = bf16_rne(a - bf16_f32(hi));
    wt_hi[t] = hi;
    wt_lo[t] = lo;
}

// ---------------- split-bf16 MFMA GEMM ----------------
// out[n,DOUT] = (f(A[inperm]) @ W (+bias) (relu)) * (rs[row]?) -> out[outperm]
// 256 thr = 4 waves; block = 64 rows; wave w = rows [16w,16w+16) x all DOUT cols.

template <int DIN, int DOUT, bool RELU_IN, bool ADD_BIAS, bool RELU_OUT,
          bool SCALE_ROW, bool IN_PERM, bool OUT_PERM>
__global__ __launch_bounds__(256) void gemm_mfma(
        const float* __restrict__ A, const unsigned short* __restrict__ Wth,
        const unsigned short* __restrict__ Wtl, const float* __restrict__ bias,
        const float* __restrict__ rs, const int* __restrict__ map,
        float* __restrict__ out, int n) {
    constexpr int KC  = (DIN >= 64) ? 64 : DIN;   // real k per staged chunk
    constexpr int KCP = (KC < 32) ? 32 : KC;      // padded k (MFMA needs K>=32)
    constexpr int NKC = DIN / KC;
    constexpr int KS  = KCP / 32;                 // mfma k-steps per chunk
    constexpr int NT  = DOUT / 16;                // n-tiles per wave
    constexpr int LDB = KCP * 2 + 16;             // LDS row stride (bytes); 2-way-free b128
    __shared__ __align__(16) unsigned char lds[(128 + 2 * DOUT) * LDB];
    unsigned char* Ah = lds;
    unsigned char* Al = lds + 64 * LDB;
    unsigned char* Wh = lds + 128 * LDB;
    unsigned char* Wl = lds + (size_t)(128 + DOUT) * LDB;

    const int row0 = blockIdx.x * 64;
    const int lane = threadIdx.x & 63;
    const int wave = __builtin_amdgcn_readfirstlane((int)(threadIdx.x >> 6));
    const int l15 = lane & 15, lhi = lane >> 4;

    f32x4 acc[NT];
#pragma unroll
    for (int t = 0; t < NT; ++t) acc[t] = (f32x4){0.f, 0.f, 0.f, 0.f};

    for (int kc = 0; kc < NKC; ++kc) {
        // ---- stage A chunk: f32 -> bf16 hi/lo ----
        constexpr int AG = KCP / 4;               // float4 groups per row
        for (int i = threadIdx.x; i < 64 * AG; i += 256) {
            int r = i / AG, j = i % AG;
            us4 h4 = {0, 0, 0, 0}, l4 = {0, 0, 0, 0};
            int gr = row0 + r;
            if (gr < n && j * 4 < KC) {
                int ar = IN_PERM ? map[gr] : gr;
                float4 v = *(const float4*)(A + (size_t)ar * DIN + kc * KC + j * 4);
                if (RELU_IN) {
                    v.x = fmaxf(v.x, 0.f); v.y = fmaxf(v.y, 0.f);
                    v.z = fmaxf(v.z, 0.f); v.w = fmaxf(v.w, 0.f);
                }
                h4[0] = bf16_rne(v.x); l4[0] = bf16_rne(v.x - bf16_f32(h4[0]));
                h4[1] = bf16_rne(v.y); l4[1] = bf16_rne(v.y - bf16_f32(h4[1]));
                h4[2] = bf16_rne(v.z); l4[2] = bf16_rne(v.z - bf16_f32(h4[2]));
                h4[3] = bf16_rne(v.w); l4[3] = bf16_rne(v.w - bf16_f32(h4[3]));
            }
            *(us4*)(Ah + r * LDB + j * 8) = h4;
            *(us4*)(Al + r * LDB + j * 8) = l4;
        }
        // ---- stage W chunk (already transposed+split in global) ----
        constexpr int WG = KCP / 8;               // ushort8 per row
        for (int i = threadIdx.x; i < DOUT * WG; i += 256) {
            int c = i / WG, j = i % WG;
            us8 h8 = {0, 0, 0, 0, 0, 0, 0, 0}, l8 = {0, 0, 0, 0, 0, 0, 0, 0};
            if (j * 8 < KC) {
                h8 = *(const us8*)(Wth + (size_t)c * DIN + kc * KC + j * 8);
                l8 = *(const us8*)(Wtl + (size_t)c * DIN + kc * KC + j * 8);
            }
            *(us8*)(Wh + c * LDB + j * 16) = h8;
            *(us8*)(Wl + c * LDB + j * 16) = l8;
        }
        __syncthreads();

        // ---- MFMA: acc += ah*bh + ah*bl + al*bh ----
        const unsigned char* arh = Ah + (wave * 16 + l15) * LDB + lhi * 16;
        const unsigned char* arl = Al + (wave * 16 + l15) * LDB + lhi * 16;
#pragma unroll
        for (int ks = 0; ks < KS; ++ks) {
            bf16x8 ah = *(const bf16x8*)(arh + ks * 64);
            bf16x8 al = *(const bf16x8*)(arl + ks * 64);
#pragma unroll
            for (int t = 0; t < NT; ++t) {
                bf16x8 bh = *(const bf16x8*)(Wh + (t * 16 + l15) * LDB + lhi * 16 + ks * 64);
                bf16x8 bl = *(const bf16x8*)(Wl + (t * 16 + l15) * LDB + lhi * 16 + ks * 64);
                acc[t] = __builtin_amdgcn_mfma_f32_16x16x32_bf16(ah, bh, acc[t], 0, 0, 0);
                acc[t] = __builtin_amdgcn_mfma_f32_16x16x32_bf16(ah, bl, acc[t], 0, 0, 0);
                acc[t] = __builtin_amdgcn_mfma_f32_16x16x32_bf16(al, bh, acc[t], 0, 0, 0);
            }
        }
        __syncthreads();
    }

    // ---- epilogue: C/D layout col=l&15, row=(l>>4)*4+r ----
    const int rbase = row0 + wave * 16 + (lhi << 2);
    float rsv[4]; int om[4];
#pragma unroll
    for (int r = 0; r < 4; ++r) {
        int row = rbase + r;
        bool ok = row < n;
        rsv[r] = (SCALE_ROW && ok) ? rs[row] : 1.0f;
        om[r] = ok ? (OUT_PERM ? map[row] : row) : -1;
    }
#pragma unroll
    for (int t = 0; t < NT; ++t) {
        int colb = t * 16 + l15;
        float b = ADD_BIAS ? bias[colb] : 0.f;
#pragma unroll
        for (int r = 0; r < 4; ++r) {
            if (om[r] < 0) continue;
            float v = acc[t][r] + b;
            if (RELU_OUT) v = fmaxf(v, 0.f);
            if (SCALE_ROW) v *= rsv[r];
            out[(size_t)om[r] * DOUT + colb] = v;
        }
    }
}

// ---------------- propagation: thread-per-(slot,d4) CSR gather ----------------

template <int DOUT, bool RELU_IN, bool SHARP, bool ADD_BIAS, bool POST_SCALE>
__global__ __launch_bounds__(256) void gather_tpd(
        const float* __restrict__ u, const int* __restrict__ offs,
        const int* __restrict__ src, const float* __restrict__ dinv,
        const float* __restrict__ ps, const float* __restrict__ bias,
        float* __restrict__ out, int n) {
    constexpr int DQ = DOUT / 4;
    constexpr int SH = (DOUT == 64) ? 4 : (DOUT == 32) ? 3 : 2;
    int idx = blockIdx.x * blockDim.x + threadIdx.x;
    int node = idx >> SH;
    if (node >= n) return;
    int d4 = (idx & (DQ - 1)) << 2;

    float4 self4 = *(const float4*)(u + (size_t)node * DOUT + d4);
    if (RELU_IN) {
        self4.x = fmaxf(self4.x, 0.f); self4.y = fmaxf(self4.y, 0.f);
        self4.z = fmaxf(self4.z, 0.f); self4.w = fmaxf(self4.w, 0.f);
    }
    float4 acc = make_float4(0.f, 0.f, 0.f, 0.f);
    int s = offs[node], e1 = offs[node + 1];
    for (int e = s; e < e1; ++e) {
        int r = src[e];
        float4 v = *(const float4*)(u + (size_t)r * DOUT + d4);
        if (RELU_IN) {
            v.x = fmaxf(v.x, 0.f); v.y = fmaxf(v.y, 0.f);
            v.z = fmaxf(v.z, 0.f); v.w = fmaxf(v.w, 0.f);
        }
        acc.x += v.x; acc.y += v.y; acc.z += v.z; acc.w += v.w;
    }
    float dv = dinv[node];
    float4 t;
    if (SHARP) {
        t.x = dv * (2.f * self4.x - acc.x); t.y = dv * (2.f * self4.y - acc.y);
        t.z = dv * (2.f * self4.z - acc.z); t.w = dv * (2.f * self4.w - acc.w);
    } else {
        t.x = dv * (acc.x + self4.x); t.y = dv * (acc.y + self4.y);
        t.z = dv * (acc.z + self4.z); t.w = dv * (acc.w + self4.w);
    }
    if (ADD_BIAS) {
        float4 b4 = *(const float4*)(bias + d4);
        t.x += b4.x; t.y += b4.y; t.z += b4.z; t.w += b4.w;
    }
    if (POST_SCALE) {
        float p = ps[node];
        t.x *= p; t.y *= p; t.z *= p; t.w *= p;
    }
    *(float4*)(out + (size_t)node * DOUT + d4) = t;
}

// ---------------- host orchestration ----------------

extern "C" void kernel_launch(void* const* d_in, const int* in_sizes, int n_in,
                              void* d_out, int out_size, void* d_ws, size_t ws_size,
                              hipStream_t stream) {
    const int T = 128;
    const int n = in_sizes[0] / T;        // 100000
    const int E = in_sizes[1] / 2;        // 600000

    const float* x   = (const float*)d_in[0];
    const int* eidx  = (const int*)d_in[1];
    const int* row   = eidx;
    const int* col   = eidx + E;
    const float* We1 = (const float*)d_in[2];
    const float* be1 = (const float*)d_in[3];
    const float* We2 = (const float*)d_in[4];
    const float* be2 = (const float*)d_in[5];
    const float* We3 = (const float*)d_in[6];
    const float* be3 = (const float*)d_in[7];
    const float* Wd1 = (const float*)d_in[8];
    const float* bd1 = (const float*)d_in[9];
    const float* Wd2 = (const float*)d_in[10];
    const float* bd2 = (const float*)d_in[11];
    const float* Wd3 = (const float*)d_in[12];
    const float* bd3 = (const float*)d_in[13];
    float* out = (float*)d_out;

    // workspace layout (all 16B aligned)
    char* base = (char*)d_ws;
    int*   deg     = (int*)base;   base += (size_t)n * 4;
    int*   degp    = (int*)base;   base += (size_t)n * 4;
    int*   offs    = (int*)base;   base += (size_t)(n + 4) * 4;
    int*   cursor  = (int*)base;   base += (size_t)(n + 4) * 4;
    int*   bsum    = (int*)base;   base += (size_t)1024 * 4;
    int*   bhist   = (int*)base;   base += (size_t)512 * NBINS * 4;
    int*   bintot  = (int*)base;   base += (size_t)NBINS * 4;
    int*   binbase = (int*)base;   base += (size_t)NBINS * 4;
    int*   order   = (int*)base;   base += (size_t)n * 4;
    int*   slotof  = (int*)base;   base += (size_t)n * 4;
    float* dinv_s  = (float*)base; base += (size_t)n * 4;
    float* dinv_h  = (float*)base; base += (size_t)n * 4;
    int*   src     = (int*)base;   base += (size_t)E * 4;
    unsigned short* wt_hi = (unsigned short*)base; base += (size_t)21504 * 2 + 64;
    unsigned short* wt_lo = (unsigned short*)base; base += (size_t)21504 * 2 + 64;
    float* bufA    = (float*)base; base += (size_t)n * 64 * 4;
    float* bufB    = (float*)base; base += (size_t)n * 64 * 4;
    (void)ws_size;

    const int BLK = 256;
    const int nhb = ceil_div(n, SCAN_BLK);
    const int nb  = ceil_div(n + 1, SCAN_BLK);

    // --- degrees ---
    hipMemsetAsync(deg, 0, (size_t)n * 4, stream);
    deg_kernel<<<ceil_div(E, BLK), BLK, 0, stream>>>(col, deg, E);

    // --- counting sort by degree ---
    hist_kernel<<<nhb, SCAN_BLK, 0, stream>>>(deg, bhist, n);
    binscan_kernel<<<NBINS, 512, 0, stream>>>(bhist, bintot, nhb);
    base_scan_kernel<<<1, NBINS, 0, stream>>>(bintot, binbase);
    place_kernel<<<nhb, SCAN_BLK, 0, stream>>>(deg, bhist, binbase, order, slotof, n);
    dinvp_kernel<<<ceil_div(n, BLK), BLK, 0, stream>>>(deg, order, degp, dinv_s, dinv_h, n);

    // --- CSR build in slot space ---
    blk_reduce_kernel<<<nb, SCAN_BLK, 0, stream>>>(degp, bsum, n);
    bsum_scan_kernel<<<1, 1024, 0, stream>>>(bsum, nb);
    offs_kernel<<<nb, SCAN_BLK, 0, stream>>>(degp, bsum, offs, n);
    hipMemcpyAsync(cursor, offs, (size_t)n * 4, hipMemcpyDeviceToDevice, stream);
    csr_fill_kernel<<<ceil_div(E, BLK), BLK, 0, stream>>>(row, col, slotof, cursor, src, E);

    // --- W transpose + bf16 split (once per launch) ---
    WPtrs wp; wp.p[0] = We1; wp.p[1] = We2; wp.p[2] = We3;
    wp.p[3] = Wd1; wp.p[4] = Wd2; wp.p[5] = Wd3;
    wsplit_kernel<<<ceil_div(21504, BLK), BLK, 0, stream>>>(wp, wt_hi, wt_lo);

    auto gath_grid = [&](int dout) { return ceil_div(n * (dout >> 2), BLK); };
    const int ggrid = ceil_div(n, 64);

    // ================= encoder (smooth): GEMM(scale dinv_s) then gather =================
    // L1: u1 = dinv_s ⊙ (x[order] @ We1); a1 = dinv_s[c](Σu1 + u1[c]) + be1
    gemm_mfma<128, 64, false, false, false, true, true, false>
        <<<ggrid, BLK, 0, stream>>>(x, wt_hi + 0, wt_lo + 0, nullptr, dinv_s, order, bufA, n);
    gather_tpd<64, false, false, true, false><<<gath_grid(64), BLK, 0, stream>>>(
        bufA, offs, src, dinv_s, nullptr, be1, bufB, n);

    // L2: u2 = dinv_s ⊙ (relu(a1) @ We2); a2 = dinv_s[c](Σu2 + u2[c]) + be2
    gemm_mfma<64, 32, true, false, false, true, false, false>
        <<<ggrid, BLK, 0, stream>>>(bufB, wt_hi + 8192, wt_lo + 8192, nullptr, dinv_s, nullptr, bufA, n);
    gather_tpd<32, false, false, true, false><<<gath_grid(32), BLK, 0, stream>>>(
        bufA, offs, src, dinv_s, nullptr, be2, bufB, n);

    // L3: u3 = dinv_s ⊙ (relu(a2) @ We3); Z' = dinv_h ⊙ (dinv_s[c](Σu3+u3[c]) + be3)
    gemm_mfma<32, 16, true, false, false, true, false, false>
        <<<ggrid, BLK, 0, stream>>>(bufB, wt_hi + 10240, wt_lo + 10240, nullptr, dinv_s, nullptr, bufA, n);
    gather_tpd<16, false, false, true, true><<<gath_grid(16), BLK, 0, stream>>>(
        bufA, offs, src, dinv_s, dinv_h, be3, bufB, n);

    // ================= decoder (sharp): gather then GEMM(scale dinv_h) =================
    // L4: P = dinv_h[c](2 relu(Z'[c]) - Σ relu(Z'[src])); u4 = dinv_h ⊙ relu(P@Wd1+bd1)
    gather_tpd<16, true, true, false, false><<<gath_grid(16), BLK, 0, stream>>>(
        bufB, offs, src, dinv_h, nullptr, nullptr, bufA, n);
    gemm_mfma<16, 32, false, true, true, true, false, false>
        <<<ggrid, BLK, 0, stream>>>(bufA, wt_hi + 10752, wt_lo + 10752, bd1, dinv_h, nullptr, bufB, n);

    // L5: P = dinv_h[c](2 u4[c] - Σ u4); u5 = dinv_h ⊙ relu(P@Wd2+bd2)
    gather_tpd<32, false, true, false, false><<<gath_grid(32), BLK, 0, stream>>>(
        bufB, offs, src, dinv_h, nullptr, nullptr, bufA, n);
    gemm_mfma<32, 64, false, true, true, true, false, false>
        <<<ggrid, BLK, 0, stream>>>(bufA, wt_hi + 11264, wt_lo + 11264, bd2, dinv_h, nullptr, bufB, n);

    // L6: P = dinv_h[c](2 u5[c] - Σ u5); out[order] = P @ Wd3 + bd3
    gather_tpd<64, false, true, false, false><<<gath_grid(64), BLK, 0, stream>>>(
        bufB, offs, src, dinv_h, nullptr, nullptr, bufA, n);
    gemm_mfma<64, 128, false, true, false, false, false, true>
        <<<ggrid, BLK, 0, stream>>>(bufA, wt_hi + 13312, wt_lo + 13312, bd3, nullptr, order, out, n);
}

// Round 9
// 356.203 us; speedup vs baseline: 2.1874x; 1.0051x over previous
//
#include <hip/hip_runtime.h>

// GALA graph autoencoder on MI355X — round 9: gather fused into GEMM staging.
// Pipeline: degree counting-sort relabel -> slot space; weightless algebra
// prop = dinv ⊙ (A^T (dinv ⊙ h)) with self-loop folded. Each propagation is computed
// inside the consuming GEMM's A-staging loop (random CSR reads happen there; the
// intermediate prop result never touches HBM). Split-bf16 MFMA GEMM (hi*hi+hi*lo+lo*hi)
// gives f32-grade accuracy (verified: absmax identical to pure-f32 rounds).
// 7 layer kernels: GEMM1 | gather+GEMM x2 | gather | gather+GEMM x3.

static inline int ceil_div(int a, int b) { return (a + b - 1) / b; }

#define SCAN_BLK 256
#define NBINS 64

typedef short bf16x8 __attribute__((ext_vector_type(8)));
typedef float f32x4 __attribute__((ext_vector_type(4)));
typedef unsigned short us4 __attribute__((ext_vector_type(4)));
typedef unsigned short us8 __attribute__((ext_vector_type(8)));

__device__ __forceinline__ unsigned short bf16_rne(float x) {
    union { float f; unsigned u; } v; v.f = x;
    unsigned r = v.u + 0x7fffu + ((v.u >> 16) & 1u);
    return (unsigned short)(r >> 16);
}
__device__ __forceinline__ float bf16_f32(unsigned short h) {
    union { unsigned u; float f; } v; v.u = (unsigned)h << 16;
    return v.f;
}
__device__ __forceinline__ void relu4(float4& v) {
    v.x = fmaxf(v.x, 0.f); v.y = fmaxf(v.y, 0.f);
    v.z = fmaxf(v.z, 0.f); v.w = fmaxf(v.w, 0.f);
}

// ---------------- degree ----------------

__global__ void deg_kernel(const int* __restrict__ col, int* __restrict__ deg, int E) {
    int e = blockIdx.x * blockDim.x + threadIdx.x;
    if (e < E) atomicAdd(&deg[col[e]], 1);
}

// ---------------- counting sort by degree (block-aggregated, deterministic) ----------------

__global__ void hist_kernel(const int* __restrict__ deg, int* __restrict__ blockhist, int n) {
    __shared__ int lh[NBINS];
    if (threadIdx.x < NBINS) lh[threadIdx.x] = 0;
    __syncthreads();
    int i = blockIdx.x * SCAN_BLK + threadIdx.x;
    if (i < n) {
        int d = deg[i]; if (d >= NBINS) d = NBINS - 1;
        atomicAdd(&lh[d], 1);
    }
    __syncthreads();
    if (threadIdx.x < NBINS) blockhist[blockIdx.x * NBINS + threadIdx.x] = lh[threadIdx.x];
}

__global__ void binscan_kernel(int* __restrict__ blockhist, int* __restrict__ bintot, int nb) {
    __shared__ int s[512];
    int bin = blockIdx.x, t = threadIdx.x;
    int v = (t < nb) ? blockhist[t * NBINS + bin] : 0;
    s[t] = v;
    __syncthreads();
    for (int st = 1; st < 512; st <<= 1) {
        int a = (t >= st) ? s[t - st] : 0;
        __syncthreads();
        s[t] += a;
        __syncthreads();
    }
    if (t < nb) blockhist[t * NBINS + bin] = s[t] - v;
    if (t == 0) bintot[bin] = s[511];
}

__global__ void base_scan_kernel(const int* __restrict__ bintot, int* __restrict__ binbase) {
    __shared__ int s[NBINS];
    int t = threadIdx.x;
    int v = bintot[t];
    s[t] = v;
    __syncthreads();
    for (int st = 1; st < NBINS; st <<= 1) {
        int a = (t >= st) ? s[t - st] : 0;
        __syncthreads();
        s[t] += a;
        __syncthreads();
    }
    binbase[t] = s[t] - v;
}

__global__ void place_kernel(const int* __restrict__ deg, const int* __restrict__ blockhist,
                             const int* __restrict__ binbase, int* __restrict__ order,
                             int* __restrict__ slotof, int n) {
    __shared__ int lh[NBINS];
    if (threadIdx.x < NBINS) lh[threadIdx.x] = 0;
    __syncthreads();
    int i = blockIdx.x * SCAN_BLK + threadIdx.x;
    if (i < n) {
        int d = deg[i]; if (d >= NBINS) d = NBINS - 1;
        int r = atomicAdd(&lh[d], 1);
        int slot = binbase[d] + blockhist[blockIdx.x * NBINS + d] + r;
        order[slot] = i;
        slotof[i] = slot;
    }
}

__global__ void dinvp_kernel(const int* __restrict__ deg, const int* __restrict__ order,
                             int* __restrict__ degp, float* __restrict__ dinv_s,
                             float* __restrict__ dinv_h, int n) {
    int s = blockIdx.x * blockDim.x + threadIdx.x;
    if (s < n) {
        int dd = deg[order[s]];
        float d = (float)dd;
        degp[s] = dd;
        dinv_s[s] = rsqrtf(d + 1.0f);   // smooth: indeg + 1
        dinv_h[s] = rsqrtf(d + 2.0f);   // sharp:  indeg + 2
    }
}

// ---------------- CSR build (slot space) ----------------

__global__ void blk_reduce_kernel(const int* __restrict__ deg, int* __restrict__ bsum, int n) {
    __shared__ int s[SCAN_BLK];
    int i = blockIdx.x * SCAN_BLK + threadIdx.x;
    s[threadIdx.x] = (i < n) ? deg[i] : 0;
    __syncthreads();
    for (int st = SCAN_BLK / 2; st > 0; st >>= 1) {
        if (threadIdx.x < st) s[threadIdx.x] += s[threadIdx.x + st];
        __syncthreads();
    }
    if (threadIdx.x == 0) bsum[blockIdx.x] = s[0];
}

__global__ void bsum_scan_kernel(int* bsum, int nb) {
    __shared__ int s[1024];
    int t = threadIdx.x;
    int v0 = (t < nb) ? bsum[t] : 0;
    s[t] = v0;
    __syncthreads();
    for (int st = 1; st < 1024; st <<= 1) {
        int add = (t >= st) ? s[t - st] : 0;
        __syncthreads();
        s[t] += add;
        __syncthreads();
    }
    if (t < nb) bsum[t] = s[t] - v0;  // exclusive
}

__global__ void offs_kernel(const int* __restrict__ deg, const int* __restrict__ bpre,
                            int* __restrict__ offs, int n) {
    __shared__ int s[SCAN_BLK];
    int i = blockIdx.x * SCAN_BLK + threadIdx.x;
    int t = threadIdx.x;
    int v0 = (i < n) ? deg[i] : 0;
    s[t] = v0;
    __syncthreads();
    for (int st = 1; st < SCAN_BLK; st <<= 1) {
        int add = (t >= st) ? s[t - st] : 0;
        __syncthreads();
        s[t] += add;
        __syncthreads();
    }
    if (i <= n) offs[i] = bpre[blockIdx.x] + s[t] - v0;
}

__global__ void csr_fill_kernel(const int* __restrict__ row, const int* __restrict__ col,
                                const int* __restrict__ slotof, int* __restrict__ cursor,
                                int* __restrict__ src, int E) {
    int e = blockIdx.x * blockDim.x + threadIdx.x;
    if (e >= E) return;
    int cs = slotof[col[e]];
    int p = atomicAdd(&cursor[cs], 1);
    src[p] = slotof[row[e]];
}

// ---------------- W pre-transpose + split (f32 [DIN][DOUT] -> bf16 hi/lo [DOUT][DIN]) ----------------

struct WPtrs { const float* p[6]; };

__global__ void wsplit_kernel(WPtrs wp, unsigned short* __restrict__ wt_hi,
                              unsigned short* __restrict__ wt_lo) {
    const int din[6]  = {128, 64, 32, 16, 32, 64};
    const int dout[6] = {64, 32, 16, 32, 64, 128};
    const int off[6]  = {0, 8192, 10240, 10752, 11264, 13312};
    int t = blockIdx.x * blockDim.x + threadIdx.x;
    if (t >= 21504) return;
    int l = 0;
    while (l < 5 && t >= off[l + 1]) ++l;
    int idx = t - off[l];
    int c = idx / din[l], k = idx - c * din[l];
    float a = wp.p[l][k * dout[l] + c];
    unsigned short hi = bf16_rne(a);
    unsigned short lo = bf16_rne(a - bf16_f32(hi));
    wt_hi[t] = hi;
    wt_lo[t] = lo;
}

// ---------------- fused gather + split-bf16 MFMA GEMM ----------------
// Staging modes for the A-tile:
//   PLAIN:      v = A[perm(row)]                                  (L1; chunked over K)
//   SMOOTH:     v = relu( gdinv[r]*(Σ u[src] + u[r]) + gbias )    (encoder L2, L3)
//   SHARP:      v = gdinv[r]*(2*u[r] - Σ u[src])                  (decoder L5, L6)
//   SHARP_RELU: same as SHARP but relu() applied to gathered vals (decoder L4)
// Then C = A_tile @ W via 3-pass split-bf16 MFMA; epilogue fuses bias/relu/row-scale.
// WAVES waves, BM = 16*WAVES rows per block; wave w computes rows [16w,16w+16) x DOUT.

#define M_PLAIN 0
#define M_SMOOTH 1
#define M_SHARP 2
#define M_SHARP_RELU 3

template <int DIN, int DOUT, int WAVES, int MODE, bool ADD_BIAS, bool RELU_OUT,
          bool SCALE_ROW, bool IN_PERM, bool OUT_PERM>
__global__ __launch_bounds__(WAVES * 64) void gemm_fused(
        const float* __restrict__ A, const unsigned short* __restrict__ Wth,
        const unsigned short* __restrict__ Wtl, const float* __restrict__ gbias,
        const float* __restrict__ gdinv, const int* __restrict__ offs,
        const int* __restrict__ srcv, const float* __restrict__ bias,
        const float* __restrict__ rs, const int* __restrict__ map,
        float* __restrict__ out, int n) {
    constexpr int THREADS = WAVES * 64;
    constexpr int BM  = WAVES * 16;               // rows per block
    constexpr int KC  = (DIN >= 64) ? 64 : DIN;   // real k per staged chunk
    constexpr int KCP = (KC < 32) ? 32 : KC;      // padded k (MFMA needs K>=32)
    constexpr int NKC = DIN / KC;                 // chunks (==1 for gather modes)
    constexpr int KS  = KCP / 32;                 // mfma k-steps per chunk
    constexpr int NT  = DOUT / 16;                // n-tiles per wave
    constexpr int LDB = KCP * 2 + 16;             // LDS row stride (bytes)
    static_assert(MODE == M_PLAIN || NKC == 1, "gather modes need single chunk");
    __shared__ __align__(16) unsigned char lds[(2 * BM + 2 * DOUT) * LDB];
    unsigned char* Ah = lds;
    unsigned char* Al = lds + (size_t)BM * LDB;
    unsigned char* Wh = lds + (size_t)2 * BM * LDB;
    unsigned char* Wl = lds + (size_t)(2 * BM + DOUT) * LDB;

    const int row0 = blockIdx.x * BM;
    const int lane = threadIdx.x & 63;
    const int wave = __builtin_amdgcn_readfirstlane((int)(threadIdx.x >> 6));
    const int l15 = lane & 15, lhi = lane >> 4;

    f32x4 acc[NT];
#pragma unroll
    for (int t = 0; t < NT; ++t) acc[t] = (f32x4){0.f, 0.f, 0.f, 0.f};

    for (int kc = 0; kc < NKC; ++kc) {
        // ---- stage A chunk: compute (plain or gathered) f32, split -> bf16 hi/lo ----
        constexpr int AG = KCP / 4;               // float4 groups per row
        for (int i = threadIdx.x; i < BM * AG; i += THREADS) {
            int r = i / AG, j = i % AG;
            us4 h4 = {0, 0, 0, 0}, l4 = {0, 0, 0, 0};
            int gr = row0 + r;
            if (gr < n && j * 4 < KC) {
                float4 v;
                if (MODE == M_PLAIN) {
                    int ar = IN_PERM ? map[gr] : gr;
                    v = *(const float4*)(A + (size_t)ar * DIN + kc * KC + j * 4);
                } else {
                    float4 self = *(const float4*)(A + (size_t)gr * DIN + j * 4);
                    if (MODE == M_SHARP_RELU) relu4(self);
                    float4 g = make_float4(0.f, 0.f, 0.f, 0.f);
                    int s0 = offs[gr], e1 = offs[gr + 1];
                    for (int e = s0; e < e1; ++e) {
                        int rd = srcv[e];
                        float4 t = *(const float4*)(A + (size_t)rd * DIN + j * 4);
                        if (MODE == M_SHARP_RELU) relu4(t);
                        g.x += t.x; g.y += t.y; g.z += t.z; g.w += t.w;
                    }
                    float dv = gdinv[gr];
                    if (MODE == M_SMOOTH) {
                        float4 b4 = *(const float4*)(gbias + j * 4);
                        v.x = fmaf(dv, g.x + self.x, b4.x);
                        v.y = fmaf(dv, g.y + self.y, b4.y);
                        v.z = fmaf(dv, g.z + self.z, b4.z);
                        v.w = fmaf(dv, g.w + self.w, b4.w);
                        relu4(v);
                    } else {
                        v.x = dv * (2.f * self.x - g.x);
                        v.y = dv * (2.f * self.y - g.y);
                        v.z = dv * (2.f * self.z - g.z);
                        v.w = dv * (2.f * self.w - g.w);
                    }
                }
                h4[0] = bf16_rne(v.x); l4[0] = bf16_rne(v.x - bf16_f32(h4[0]));
                h4[1] = bf16_rne(v.y); l4[1] = bf16_rne(v.y - bf16_f32(h4[1]));
                h4[2] = bf16_rne(v.z); l4[2] = bf16_rne(v.z - bf16_f32(h4[2]));
                h4[3] = bf16_rne(v.w); l4[3] = bf16_rne(v.w - bf16_f32(h4[3]));
            }
            *(us4*)(Ah + (size_t)r * LDB + j * 8) = h4;
            *(us4*)(Al + (size_t)r * LDB + j * 8) = l4;
        }
        // ---- stage W chunk (already transposed+split in global) ----
        constexpr int WG = KCP / 8;               // ushort8 per row
        for (int i = threadIdx.x; i < DOUT * WG; i += THREADS) {
            int c = i / WG, j = i % WG;
            us8 h8 = {0, 0, 0, 0, 0, 0, 0, 0}, l8 = {0, 0, 0, 0, 0, 0, 0, 0};
            if (j * 8 < KC) {
                h8 = *(const us8*)(Wth + (size_t)c * DIN + kc * KC + j * 8);
                l8 = *(const us8*)(Wtl + (size_t)c * DIN + kc * KC + j * 8);
            }
            *(us8*)(Wh + (size_t)c * LDB + j * 16) = h8;
            *(us8*)(Wl + (size_t)c * LDB + j * 16) = l8;
        }
        __syncthreads();

        // ---- MFMA: acc += ah*bh + ah*bl + al*bh ----
        const unsigned char* arh = Ah + (size_t)(wave * 16 + l15) * LDB + lhi * 16;
        const unsigned char* arl = Al + (size_t)(wave * 16 + l15) * LDB + lhi * 16;
#pragma unroll
        for (int ks = 0; ks < KS; ++ks) {
            bf16x8 ah = *(const bf16x8*)(arh + ks * 64);
            bf16x8 al = *(const bf16x8*)(arl + ks * 64);
#pragma unroll
            for (int t = 0; t < NT; ++t) {
                bf16x8 bh = *(const bf16x8*)(Wh + (size_t)(t * 16 + l15) * LDB + lhi * 16 + ks * 64);
                bf16x8 bl = *(const bf16x8*)(Wl + (size_t)(t * 16 + l15) * LDB + lhi * 16 + ks * 64);
                acc[t] = __builtin_amdgcn_mfma_f32_16x16x32_bf16(ah, bh, acc[t], 0, 0, 0);
                acc[t] = __builtin_amdgcn_mfma_f32_16x16x32_bf16(ah, bl, acc[t], 0, 0, 0);
                acc[t] = __builtin_amdgcn_mfma_f32_16x16x32_bf16(al, bh, acc[t], 0, 0, 0);
            }
        }
        if (NKC > 1) __syncthreads();
    }

    // ---- epilogue: C/D layout col=l&15, row=(l>>4)*4+r ----
    const int rbase = row0 + wave * 16 + (lhi << 2);
    float rsv[4]; int om[4];
#pragma unroll
    for (int r = 0; r < 4; ++r) {
        int row = rbase + r;
        bool ok = row < n;
        rsv[r] = (SCALE_ROW && ok) ? rs[row] : 1.0f;
        om[r] = ok ? (OUT_PERM ? map[row] : row) : -1;
    }
#pragma unroll
    for (int t = 0; t < NT; ++t) {
        int colb = t * 16 + l15;
        float b = ADD_BIAS ? bias[colb] : 0.f;
#pragma unroll
        for (int r = 0; r < 4; ++r) {
            if (om[r] < 0) continue;
            float v = acc[t][r] + b;
            if (RELU_OUT) v = fmaxf(v, 0.f);
            if (SCALE_ROW) v *= rsv[r];
            out[(size_t)om[r] * DOUT + colb] = v;
        }
    }
}

// ---------------- standalone gather (L3->L4 boundary must materialize) ----------------

template <int DOUT, bool RELU_IN, bool SHARP, bool ADD_BIAS, bool POST_SCALE>
__global__ __launch_bounds__(256) void gather_tpd(
        const float* __restrict__ u, const int* __restrict__ offs,
        const int* __restrict__ src, const float* __restrict__ dinv,
        const float* __restrict__ ps, const float* __restrict__ bias,
        float* __restrict__ out, int n) {
    constexpr int DQ = DOUT / 4;
    constexpr int SH = (DOUT == 64) ? 4 : (DOUT == 32) ? 3 : 2;
    int idx = blockIdx.x * blockDim.x + threadIdx.x;
    int node = idx >> SH;
    if (node >= n) return;
    int d4 = (idx & (DQ - 1)) << 2;

    float4 self4 = *(const float4*)(u + (size_t)node * DOUT + d4);
    if (RELU_IN) relu4(self4);
    float4 acc = make_float4(0.f, 0.f, 0.f, 0.f);
    int s = offs[node], e1 = offs[node + 1];
    for (int e = s; e < e1; ++e) {
        int r = src[e];
        float4 v = *(const float4*)(u + (size_t)r * DOUT + d4);
        if (RELU_IN) relu4(v);
        acc.x += v.x; acc.y += v.y; acc.z += v.z; acc.w += v.w;
    }
    float dv = dinv[node];
    float4 t;
    if (SHARP) {
        t.x = dv * (2.f * self4.x - acc.x); t.y = dv * (2.f * self4.y - acc.y);
        t.z = dv * (2.f * self4.z - acc.z); t.w = dv * (2.f * self4.w - acc.w);
    } else {
        t.x = dv * (acc.x + self4.x); t.y = dv * (acc.y + self4.y);
        t.z = dv * (acc.z + self4.z); t.w = dv * (acc.w + self4.w);
    }
    if (ADD_BIAS) {
        float4 b4 = *(const float4*)(bias + d4);
        t.x += b4.x; t.y += b4.y; t.z += b4.z; t.w += b4.w;
    }
    if (POST_SCALE) {
        float p = ps[node];
        t.x *= p; t.y *= p; t.z *= p; t.w *= p;
    }
    *(float4*)(out + (size_t)node * DOUT + d4) = t;
}

// ---------------- host orchestration ----------------

extern "C" void kernel_launch(void* const* d_in, const int* in_sizes, int n_in,
                              void* d_out, int out_size, void* d_ws, size_t ws_size,
                              hipStream_t stream) {
    const int T = 128;
    const int n = in_sizes[0] / T;        // 100000
    const int E = in_sizes[1] / 2;        // 600000

    const float* x   = (const float*)d_in[0];
    const int* eidx  = (const int*)d_in[1];
    const int* row   = eidx;
    const int* col   = eidx + E;
    const float* We1 = (const float*)d_in[2];
    const float* be1 = (const float*)d_in[3];
    const float* We2 = (const float*)d_in[4];
    const float* be2 = (const float*)d_in[5];
    const float* We3 = (const float*)d_in[6];
    const float* be3 = (const float*)d_in[7];
    const float* Wd1 = (const float*)d_in[8];
    const float* bd1 = (const float*)d_in[9];
    const float* Wd2 = (const float*)d_in[10];
    const float* bd2 = (const float*)d_in[11];
    const float* Wd3 = (const float*)d_in[12];
    const float* bd3 = (const float*)d_in[13];
    float* out = (float*)d_out;

    // workspace layout (all 16B aligned)
    char* base = (char*)d_ws;
    int*   deg     = (int*)base;   base += (size_t)n * 4;
    int*   degp    = (int*)base;   base += (size_t)n * 4;
    int*   offs    = (int*)base;   base += (size_t)(n + 4) * 4;
    int*   cursor  = (int*)base;   base += (size_t)(n + 4) * 4;
    int*   bsum    = (int*)base;   base += (size_t)1024 * 4;
    int*   bhist   = (int*)base;   base += (size_t)512 * NBINS * 4;
    int*   bintot  = (int*)base;   base += (size_t)NBINS * 4;
    int*   binbase = (int*)base;   base += (size_t)NBINS * 4;
    int*   order   = (int*)base;   base += (size_t)n * 4;
    int*   slotof  = (int*)base;   base += (size_t)n * 4;
    float* dinv_s  = (float*)base; base += (size_t)n * 4;
    float* dinv_h  = (float*)base; base += (size_t)n * 4;
    int*   src     = (int*)base;   base += (size_t)E * 4;
    unsigned short* wt_hi = (unsigned short*)base; base += (size_t)21504 * 2 + 64;
    unsigned short* wt_lo = (unsigned short*)base; base += (size_t)21504 * 2 + 64;
    float* bufA    = (float*)base; base += (size_t)n * 64 * 4;
    float* bufB    = (float*)base; base += (size_t)n * 64 * 4;
    (void)ws_size;

    const int BLK = 256;
    const int nhb = ceil_div(n, SCAN_BLK);
    const int nb  = ceil_div(n + 1, SCAN_BLK);

    // --- degrees ---
    hipMemsetAsync(deg, 0, (size_t)n * 4, stream);
    deg_kernel<<<ceil_div(E, BLK), BLK, 0, stream>>>(col, deg, E);

    // --- counting sort by degree ---
    hist_kernel<<<nhb, SCAN_BLK, 0, stream>>>(deg, bhist, n);
    binscan_kernel<<<NBINS, 512, 0, stream>>>(bhist, bintot, nhb);
    base_scan_kernel<<<1, NBINS, 0, stream>>>(bintot, binbase);
    place_kernel<<<nhb, SCAN_BLK, 0, stream>>>(deg, bhist, binbase, order, slotof, n);
    dinvp_kernel<<<ceil_div(n, BLK), BLK, 0, stream>>>(deg, order, degp, dinv_s, dinv_h, n);

    // --- CSR build in slot space ---
    blk_reduce_kernel<<<nb, SCAN_BLK, 0, stream>>>(degp, bsum, n);
    bsum_scan_kernel<<<1, 1024, 0, stream>>>(bsum, nb);
    offs_kernel<<<nb, SCAN_BLK, 0, stream>>>(degp, bsum, offs, n);
    hipMemcpyAsync(cursor, offs, (size_t)n * 4, hipMemcpyDeviceToDevice, stream);
    csr_fill_kernel<<<ceil_div(E, BLK), BLK, 0, stream>>>(row, col, slotof, cursor, src, E);

    // --- W transpose + bf16 split (once per launch) ---
    WPtrs wp; wp.p[0] = We1; wp.p[1] = We2; wp.p[2] = We3;
    wp.p[3] = Wd1; wp.p[4] = Wd2; wp.p[5] = Wd3;
    wsplit_kernel<<<ceil_div(21504, BLK), BLK, 0, stream>>>(wp, wt_hi, wt_lo);

    // K1: u1 = dinv_s ⊙ (x[order] @ We1)          [PLAIN, 4 waves, chunked K=128]
    gemm_fused<128, 64, 4, M_PLAIN, false, false, true, true, false>
        <<<ceil_div(n, 64), 256, 0, stream>>>(
        x, wt_hi + 0, wt_lo + 0, nullptr, nullptr, nullptr, nullptr,
        nullptr, dinv_s, order, bufA, n);

    // K2: a1 = relu(dinv_s[c](Σu1+u1[c]) + be1); u2 = dinv_s ⊙ (a1 @ We2)  [SMOOTH]
    gemm_fused<64, 32, 8, M_SMOOTH, false, false, true, false, false>
        <<<ceil_div(n, 128), 512, 0, stream>>>(
        bufA, wt_hi + 8192, wt_lo + 8192, be1, dinv_s, offs, src,
        nullptr, dinv_s, nullptr, bufB, n);

    // K3: a2 = relu(dinv_s[c](Σu2+u2[c]) + be2); u3 = dinv_s ⊙ (a2 @ We3)  [SMOOTH]
    gemm_fused<32, 16, 8, M_SMOOTH, false, false, true, false, false>
        <<<ceil_div(n, 128), 512, 0, stream>>>(
        bufB, wt_hi + 10240, wt_lo + 10240, be2, dinv_s, offs, src,
        nullptr, dinv_s, nullptr, bufA, n);

    // K4: Z' = dinv_h ⊙ (dinv_s[c](Σu3+u3[c]) + be3)   [standalone smooth gather]
    gather_tpd<16, false, false, true, true><<<ceil_div(n * 4, BLK), BLK, 0, stream>>>(
        bufA, offs, src, dinv_s, dinv_h, be3, bufB, n);

    // K5: P4 = dinv_h[c](2 relu(Z'[c]) - Σ relu(Z'[src])); u4 = dinv_h ⊙ relu(P4@Wd1+bd1)
    gemm_fused<16, 32, 8, M_SHARP_RELU, true, true, true, false, false>
        <<<ceil_div(n, 128), 512, 0, stream>>>(
        bufB, wt_hi + 10752, wt_lo + 10752, nullptr, dinv_h, offs, src,
        bd1, dinv_h, nullptr, bufA, n);

    // K6: P5 = dinv_h[c](2 u4[c] - Σ u4); u5 = dinv_h ⊙ relu(P5@Wd2+bd2)   [SHARP]
    gemm_fused<32, 64, 8, M_SHARP, true, true, true, false, false>
        <<<ceil_div(n, 128), 512, 0, stream>>>(
        bufA, wt_hi + 11264, wt_lo + 11264, nullptr, dinv_h, offs, src,
        bd2, dinv_h, nullptr, bufB, n);

    // K7: P6 = dinv_h[c](2 u5[c] - Σ u5); out[order] = P6 @ Wd3 + bd3      [SHARP]
    gemm_fused<64, 128, 8, M_SHARP, true, false, false, false, true>
        <<<ceil_div(n, 128), 512, 0, stream>>>(
        bufB, wt_hi + 13312, wt_lo + 13312, nullptr, dinv_h, offs, src,
        bd3, nullptr, order, out, n);
}

// Round 10
// 317.525 us; speedup vs baseline: 2.4539x; 1.1218x over previous
//
#include <hip/hip_runtime.h>

// GALA graph autoencoder on MI355X — round 10: MLP-unrolled gathers + low-LDS chunked MFMA.
// Pipeline: degree counting-sort relabel -> slot space; weightless algebra
// prop = dinv ⊙ (A^T (dinv ⊙ h)) with self-loop folded; propagation fused into the
// consuming GEMM's A-staging (random CSR reads there; prop result never hits HBM).
// Split-bf16 MFMA (hi*hi+hi*lo+lo*hi) = f32-grade accuracy.
// NEW: (1) 4-way unrolled edge loops -> 4x memory-level parallelism on random reads;
//      (2) KC=32 chunks -> LDS <= 40KB/block -> 4 blocks x 8 waves = 32 waves/CU.

static inline int ceil_div(int a, int b) { return (a + b - 1) / b; }

#define SCAN_BLK 256
#define NBINS 64

typedef short bf16x8 __attribute__((ext_vector_type(8)));
typedef float f32x4 __attribute__((ext_vector_type(4)));
typedef unsigned short us4 __attribute__((ext_vector_type(4)));
typedef unsigned short us8 __attribute__((ext_vector_type(8)));

__device__ __forceinline__ unsigned short bf16_rne(float x) {
    union { float f; unsigned u; } v; v.f = x;
    unsigned r = v.u + 0x7fffu + ((v.u >> 16) & 1u);
    return (unsigned short)(r >> 16);
}
__device__ __forceinline__ float bf16_f32(unsigned short h) {
    union { unsigned u; float f; } v; v.u = (unsigned)h << 16;
    return v.f;
}
__device__ __forceinline__ void relu4(float4& v) {
    v.x = fmaxf(v.x, 0.f); v.y = fmaxf(v.y, 0.f);
    v.z = fmaxf(v.z, 0.f); v.w = fmaxf(v.w, 0.f);
}

// ---------------- degree ----------------

__global__ void deg_kernel(const int* __restrict__ col, int* __restrict__ deg, int E) {
    int e = blockIdx.x * blockDim.x + threadIdx.x;
    if (e < E) atomicAdd(&deg[col[e]], 1);
}

// ---------------- counting sort by degree (block-aggregated, deterministic) ----------------

__global__ void hist_kernel(const int* __restrict__ deg, int* __restrict__ blockhist, int n) {
    __shared__ int lh[NBINS];
    if (threadIdx.x < NBINS) lh[threadIdx.x] = 0;
    __syncthreads();
    int i = blockIdx.x * SCAN_BLK + threadIdx.x;
    if (i < n) {
        int d = deg[i]; if (d >= NBINS) d = NBINS - 1;
        atomicAdd(&lh[d], 1);
    }
    __syncthreads();
    if (threadIdx.x < NBINS) blockhist[blockIdx.x * NBINS + threadIdx.x] = lh[threadIdx.x];
}

__global__ void binscan_kernel(int* __restrict__ blockhist, int* __restrict__ bintot, int nb) {
    __shared__ int s[512];
    int bin = blockIdx.x, t = threadIdx.x;
    int v = (t < nb) ? blockhist[t * NBINS + bin] : 0;
    s[t] = v;
    __syncthreads();
    for (int st = 1; st < 512; st <<= 1) {
        int a = (t >= st) ? s[t - st] : 0;
        __syncthreads();
        s[t] += a;
        __syncthreads();
    }
    if (t < nb) blockhist[t * NBINS + bin] = s[t] - v;
    if (t == 0) bintot[bin] = s[511];
}

__global__ void base_scan_kernel(const int* __restrict__ bintot, int* __restrict__ binbase) {
    __shared__ int s[NBINS];
    int t = threadIdx.x;
    int v = bintot[t];
    s[t] = v;
    __syncthreads();
    for (int st = 1; st < NBINS; st <<= 1) {
        int a = (t >= st) ? s[t - st] : 0;
        __syncthreads();
        s[t] += a;
        __syncthreads();
    }
    binbase[t] = s[t] - v;
}

__global__ void place_kernel(const int* __restrict__ deg, const int* __restrict__ blockhist,
                             const int* __restrict__ binbase, int* __restrict__ order,
                             int* __restrict__ slotof, int n) {
    __shared__ int lh[NBINS];
    if (threadIdx.x < NBINS) lh[threadIdx.x] = 0;
    __syncthreads();
    int i = blockIdx.x * SCAN_BLK + threadIdx.x;
    if (i < n) {
        int d = deg[i]; if (d >= NBINS) d = NBINS - 1;
        int r = atomicAdd(&lh[d], 1);
        int slot = binbase[d] + blockhist[blockIdx.x * NBINS + d] + r;
        order[slot] = i;
        slotof[i] = slot;
    }
}

__global__ void dinvp_kernel(const int* __restrict__ deg, const int* __restrict__ order,
                             int* __restrict__ degp, float* __restrict__ dinv_s,
                             float* __restrict__ dinv_h, int n) {
    int s = blockIdx.x * blockDim.x + threadIdx.x;
    if (s < n) {
        int dd = deg[order[s]];
        float d = (float)dd;
        degp[s] = dd;
        dinv_s[s] = rsqrtf(d + 1.0f);   // smooth: indeg + 1
        dinv_h[s] = rsqrtf(d + 2.0f);   // sharp:  indeg + 2
    }
}

// ---------------- CSR build (slot space) ----------------

__global__ void blk_reduce_kernel(const int* __restrict__ deg, int* __restrict__ bsum, int n) {
    __shared__ int s[SCAN_BLK];
    int i = blockIdx.x * SCAN_BLK + threadIdx.x;
    s[threadIdx.x] = (i < n) ? deg[i] : 0;
    __syncthreads();
    for (int st = SCAN_BLK / 2; st > 0; st >>= 1) {
        if (threadIdx.x < st) s[threadIdx.x] += s[threadIdx.x + st];
        __syncthreads();
    }
    if (threadIdx.x == 0) bsum[blockIdx.x] = s[0];
}

__global__ void bsum_scan_kernel(int* bsum, int nb) {
    __shared__ int s[1024];
    int t = threadIdx.x;
    int v0 = (t < nb) ? bsum[t] : 0;
    s[t] = v0;
    __syncthreads();
    for (int st = 1; st < 1024; st <<= 1) {
        int add = (t >= st) ? s[t - st] : 0;
        __syncthreads();
        s[t] += add;
        __syncthreads();
    }
    if (t < nb) bsum[t] = s[t] - v0;  // exclusive
}

__global__ void offs_kernel(const int* __restrict__ deg, const int* __restrict__ bpre,
                            int* __restrict__ offs, int n) {
    __shared__ int s[SCAN_BLK];
    int i = blockIdx.x * SCAN_BLK + threadIdx.x;
    int t = threadIdx.x;
    int v0 = (i < n) ? deg[i] : 0;
    s[t] = v0;
    __syncthreads();
    for (int st = 1; st < SCAN_BLK; st <<= 1) {
        int add = (t >= st) ? s[t - st] : 0;
        __syncthreads();
        s[t] += add;
        __syncthreads();
    }
    if (i <= n) offs[i] = bpre[blockIdx.x] + s[t] - v0;
}

__global__ void csr_fill_kernel(const int* __restrict__ row, const int* __restrict__ col,
                                const int* __restrict__ slotof, int* __restrict__ cursor,
                                int* __restrict__ src, int E) {
    int e = blockIdx.x * blockDim.x + threadIdx.x;
    if (e >= E) return;
    int cs = slotof[col[e]];
    int p = atomicAdd(&cursor[cs], 1);
    src[p] = slotof[row[e]];
}

// ---------------- W pre-transpose + split (f32 [DIN][DOUT] -> bf16 hi/lo [DOUT][DIN]) ----------------

struct WPtrs { const float* p[6]; };

__global__ void wsplit_kernel(WPtrs wp, unsigned short* __restrict__ wt_hi,
                              unsigned short* __restrict__ wt_lo) {
    const int din[6]  = {128, 64, 32, 16, 32, 64};
    const int dout[6] = {64, 32, 16, 32, 64, 128};
    const int off[6]  = {0, 8192, 10240, 10752, 11264, 13312};
    int t = blockIdx.x * blockDim.x + threadIdx.x;
    if (t >= 21504) return;
    int l = 0;
    while (l < 5 && t >= off[l + 1]) ++l;
    int idx = t - off[l];
    int c = idx / din[l], k = idx - c * din[l];
    float a = wp.p[l][k * dout[l] + c];
    unsigned short hi = bf16_rne(a);
    unsigned short lo = bf16_rne(a - bf16_f32(hi));
    wt_hi[t] = hi;
    wt_lo[t] = lo;
}

// ---------------- fused gather + split-bf16 MFMA GEMM ----------------
// Staging modes (per k-chunk, k-sliced):
//   PLAIN:      v = A[perm(row)][kslice]
//   SMOOTH:     v = relu( gdinv[r]*(Σ u[src] + u[r]) + gbias )
//   SHARP:      v = gdinv[r]*(2*u[r] - Σ u[src])
//   SHARP_RELU: same as SHARP, relu applied to gathered values
// Edge loops 4-way unrolled for memory-level parallelism.

#define M_PLAIN 0
#define M_SMOOTH 1
#define M_SHARP 2
#define M_SHARP_RELU 3

template <int DIN, int DOUT, int WAVES, int MODE, bool ADD_BIAS, bool RELU_OUT,
          bool SCALE_ROW, bool IN_PERM, bool OUT_PERM>
__global__ __launch_bounds__(WAVES * 64) void gemm_fused(
        const float* __restrict__ A, const unsigned short* __restrict__ Wth,
        const unsigned short* __restrict__ Wtl, const float* __restrict__ gbias,
        const float* __restrict__ gdinv, const int* __restrict__ offs,
        const int* __restrict__ srcv, const float* __restrict__ bias,
        const float* __restrict__ rs, const int* __restrict__ map,
        float* __restrict__ out, int n) {
    constexpr int THREADS = WAVES * 64;
    constexpr int BM  = WAVES * 16;               // rows per block
    constexpr int KC  = (DIN >= 32) ? 32 : DIN;   // real k per staged chunk
    constexpr int KCP = 32;                       // padded k (MFMA K=32)
    constexpr int NKC = DIN / KC;                 // chunks
    constexpr int NT  = DOUT / 16;                // n-tiles per wave
    constexpr int LDB = KCP * 2 + 16;             // LDS row stride = 80 B (2-way-free b128)
    __shared__ __align__(16) unsigned char lds[(2 * BM + 2 * DOUT) * LDB];
    unsigned char* Ah = lds;
    unsigned char* Al = lds + (size_t)BM * LDB;
    unsigned char* Wh = lds + (size_t)2 * BM * LDB;
    unsigned char* Wl = lds + (size_t)(2 * BM + DOUT) * LDB;

    const int row0 = blockIdx.x * BM;
    const int lane = threadIdx.x & 63;
    const int wave = __builtin_amdgcn_readfirstlane((int)(threadIdx.x >> 6));
    const int l15 = lane & 15, lhi = lane >> 4;

    f32x4 acc[NT];
#pragma unroll
    for (int t = 0; t < NT; ++t) acc[t] = (f32x4){0.f, 0.f, 0.f, 0.f};

    for (int kc = 0; kc < NKC; ++kc) {
        const int kofs = kc * KC;
        // ---- stage A chunk: compute (plain or gathered) f32, split -> bf16 hi/lo ----
        constexpr int AG = KCP / 4;               // float4 groups per row (8)
        for (int i = threadIdx.x; i < BM * AG; i += THREADS) {
            int r = i / AG, j = i % AG;
            us4 h4 = {0, 0, 0, 0}, l4 = {0, 0, 0, 0};
            int gr = row0 + r;
            if (gr < n && j * 4 < KC) {
                const int j4 = j * 4;
                float4 v;
                if (MODE == M_PLAIN) {
                    int ar = IN_PERM ? map[gr] : gr;
                    v = *(const float4*)(A + (size_t)ar * DIN + kofs + j4);
                } else {
                    float4 self = *(const float4*)(A + (size_t)gr * DIN + kofs + j4);
                    if (MODE == M_SHARP_RELU) relu4(self);
                    float4 g = make_float4(0.f, 0.f, 0.f, 0.f);
                    int e = offs[gr], e1 = offs[gr + 1];
                    for (; e + 4 <= e1; e += 4) {
                        int r0 = srcv[e], r1 = srcv[e + 1], r2 = srcv[e + 2], r3 = srcv[e + 3];
                        float4 t0 = *(const float4*)(A + (size_t)r0 * DIN + kofs + j4);
                        float4 t1 = *(const float4*)(A + (size_t)r1 * DIN + kofs + j4);
                        float4 t2 = *(const float4*)(A + (size_t)r2 * DIN + kofs + j4);
                        float4 t3 = *(const float4*)(A + (size_t)r3 * DIN + kofs + j4);
                        if (MODE == M_SHARP_RELU) { relu4(t0); relu4(t1); relu4(t2); relu4(t3); }
                        g.x += (t0.x + t1.x) + (t2.x + t3.x);
                        g.y += (t0.y + t1.y) + (t2.y + t3.y);
                        g.z += (t0.z + t1.z) + (t2.z + t3.z);
                        g.w += (t0.w + t1.w) + (t2.w + t3.w);
                    }
                    for (; e < e1; ++e) {
                        int rd = srcv[e];
                        float4 t = *(const float4*)(A + (size_t)rd * DIN + kofs + j4);
                        if (MODE == M_SHARP_RELU) relu4(t);
                        g.x += t.x; g.y += t.y; g.z += t.z; g.w += t.w;
                    }
                    float dv = gdinv[gr];
                    if (MODE == M_SMOOTH) {
                        float4 b4 = *(const float4*)(gbias + kofs + j4);
                        v.x = fmaf(dv, g.x + self.x, b4.x);
                        v.y = fmaf(dv, g.y + self.y, b4.y);
                        v.z = fmaf(dv, g.z + self.z, b4.z);
                        v.w = fmaf(dv, g.w + self.w, b4.w);
                        relu4(v);
                    } else {
                        v.x = dv * (2.f * self.x - g.x);
                        v.y = dv * (2.f * self.y - g.y);
                        v.z = dv * (2.f * self.z - g.z);
                        v.w = dv * (2.f * self.w - g.w);
                    }
                }
                h4[0] = bf16_rne(v.x); l4[0] = bf16_rne(v.x - bf16_f32(h4[0]));
                h4[1] = bf16_rne(v.y); l4[1] = bf16_rne(v.y - bf16_f32(h4[1]));
                h4[2] = bf16_rne(v.z); l4[2] = bf16_rne(v.z - bf16_f32(h4[2]));
                h4[3] = bf16_rne(v.w); l4[3] = bf16_rne(v.w - bf16_f32(h4[3]));
            }
            *(us4*)(Ah + (size_t)r * LDB + j * 8) = h4;
            *(us4*)(Al + (size_t)r * LDB + j * 8) = l4;
        }
        // ---- stage W chunk (already transposed+split in global) ----
        constexpr int WG = KCP / 8;               // ushort8 per row (4)
        for (int i = threadIdx.x; i < DOUT * WG; i += THREADS) {
            int c = i / WG, j = i % WG;
            us8 h8 = {0, 0, 0, 0, 0, 0, 0, 0}, l8 = {0, 0, 0, 0, 0, 0, 0, 0};
            if (j * 8 < KC) {
                h8 = *(const us8*)(Wth + (size_t)c * DIN + kofs + j * 8);
                l8 = *(const us8*)(Wtl + (size_t)c * DIN + kofs + j * 8);
            }
            *(us8*)(Wh + (size_t)c * LDB + j * 16) = h8;
            *(us8*)(Wl + (size_t)c * LDB + j * 16) = l8;
        }
        __syncthreads();

        // ---- MFMA: acc += ah*bh + ah*bl + al*bh ----
        bf16x8 ah = *(const bf16x8*)(Ah + (size_t)(wave * 16 + l15) * LDB + lhi * 16);
        bf16x8 al = *(const bf16x8*)(Al + (size_t)(wave * 16 + l15) * LDB + lhi * 16);
#pragma unroll
        for (int t = 0; t < NT; ++t) {
            bf16x8 bh = *(const bf16x8*)(Wh + (size_t)(t * 16 + l15) * LDB + lhi * 16);
            bf16x8 bl = *(const bf16x8*)(Wl + (size_t)(t * 16 + l15) * LDB + lhi * 16);
            acc[t] = __builtin_amdgcn_mfma_f32_16x16x32_bf16(ah, bh, acc[t], 0, 0, 0);
            acc[t] = __builtin_amdgcn_mfma_f32_16x16x32_bf16(ah, bl, acc[t], 0, 0, 0);
            acc[t] = __builtin_amdgcn_mfma_f32_16x16x32_bf16(al, bh, acc[t], 0, 0, 0);
        }
        if (NKC > 1) __syncthreads();
    }

    // ---- epilogue: C/D layout col=l&15, row=(l>>4)*4+r ----
    const int rbase = row0 + wave * 16 + (lhi << 2);
    float rsv[4]; int om[4];
#pragma unroll
    for (int r = 0; r < 4; ++r) {
        int row = rbase + r;
        bool ok = row < n;
        rsv[r] = (SCALE_ROW && ok) ? rs[row] : 1.0f;
        om[r] = ok ? (OUT_PERM ? map[row] : row) : -1;
    }
#pragma unroll
    for (int t = 0; t < NT; ++t) {
        int colb = t * 16 + l15;
        float b = ADD_BIAS ? bias[colb] : 0.f;
#pragma unroll
        for (int r = 0; r < 4; ++r) {
            if (om[r] < 0) continue;
            float v = acc[t][r] + b;
            if (RELU_OUT) v = fmaxf(v, 0.f);
            if (SCALE_ROW) v *= rsv[r];
            out[(size_t)om[r] * DOUT + colb] = v;
        }
    }
}

// ---------------- standalone gather (L3->L4 boundary), 4-way unrolled ----------------

template <int DOUT, bool RELU_IN, bool SHARP, bool ADD_BIAS, bool POST_SCALE>
__global__ __launch_bounds__(256) void gather_tpd(
        const float* __restrict__ u, const int* __restrict__ offs,
        const int* __restrict__ src, const float* __restrict__ dinv,
        const float* __restrict__ ps, const float* __restrict__ bias,
        float* __restrict__ out, int n) {
    constexpr int DQ = DOUT / 4;
    constexpr int SH = (DOUT == 64) ? 4 : (DOUT == 32) ? 3 : 2;
    int idx = blockIdx.x * blockDim.x + threadIdx.x;
    int node = idx >> SH;
    if (node >= n) return;
    int d4 = (idx & (DQ - 1)) << 2;

    float4 self4 = *(const float4*)(u + (size_t)node * DOUT + d4);
    if (RELU_IN) relu4(self4);
    float4 acc = make_float4(0.f, 0.f, 0.f, 0.f);
    int e = offs[node], e1 = offs[node + 1];
    for (; e + 4 <= e1; e += 4) {
        int r0 = src[e], r1 = src[e + 1], r2 = src[e + 2], r3 = src[e + 3];
        float4 t0 = *(const float4*)(u + (size_t)r0 * DOUT + d4);
        float4 t1 = *(const float4*)(u + (size_t)r1 * DOUT + d4);
        float4 t2 = *(const float4*)(u + (size_t)r2 * DOUT + d4);
        float4 t3 = *(const float4*)(u + (size_t)r3 * DOUT + d4);
        if (RELU_IN) { relu4(t0); relu4(t1); relu4(t2); relu4(t3); }
        acc.x += (t0.x + t1.x) + (t2.x + t3.x);
        acc.y += (t0.y + t1.y) + (t2.y + t3.y);
        acc.z += (t0.z + t1.z) + (t2.z + t3.z);
        acc.w += (t0.w + t1.w) + (t2.w + t3.w);
    }
    for (; e < e1; ++e) {
        int r = src[e];
        float4 v = *(const float4*)(u + (size_t)r * DOUT + d4);
        if (RELU_IN) relu4(v);
        acc.x += v.x; acc.y += v.y; acc.z += v.z; acc.w += v.w;
    }
    float dv = dinv[node];
    float4 t;
    if (SHARP) {
        t.x = dv * (2.f * self4.x - acc.x); t.y = dv * (2.f * self4.y - acc.y);
        t.z = dv * (2.f * self4.z - acc.z); t.w = dv * (2.f * self4.w - acc.w);
    } else {
        t.x = dv * (acc.x + self4.x); t.y = dv * (acc.y + self4.y);
        t.z = dv * (acc.z + self4.z); t.w = dv * (acc.w + self4.w);
    }
    if (ADD_BIAS) {
        float4 b4 = *(const float4*)(bias + d4);
        t.x += b4.x; t.y += b4.y; t.z += b4.z; t.w += b4.w;
    }
    if (POST_SCALE) {
        float p = ps[node];
        t.x *= p; t.y *= p; t.z *= p; t.w *= p;
    }
    *(float4*)(out + (size_t)node * DOUT + d4) = t;
}

// ---------------- host orchestration ----------------

extern "C" void kernel_launch(void* const* d_in, const int* in_sizes, int n_in,
                              void* d_out, int out_size, void* d_ws, size_t ws_size,
                              hipStream_t stream) {
    const int T = 128;
    const int n = in_sizes[0] / T;        // 100000
    const int E = in_sizes[1] / 2;        // 600000

    const float* x   = (const float*)d_in[0];
    const int* eidx  = (const int*)d_in[1];
    const int* row   = eidx;
    const int* col   = eidx + E;
    const float* We1 = (const float*)d_in[2];
    const float* be1 = (const float*)d_in[3];
    const float* We2 = (const float*)d_in[4];
    const float* be2 = (const float*)d_in[5];
    const float* We3 = (const float*)d_in[6];
    const float* be3 = (const float*)d_in[7];
    const float* Wd1 = (const float*)d_in[8];
    const float* bd1 = (const float*)d_in[9];
    const float* Wd2 = (const float*)d_in[10];
    const float* bd2 = (const float*)d_in[11];
    const float* Wd3 = (const float*)d_in[12];
    const float* bd3 = (const float*)d_in[13];
    float* out = (float*)d_out;

    // workspace layout (all 16B aligned)
    char* base = (char*)d_ws;
    int*   deg     = (int*)base;   base += (size_t)n * 4;
    int*   degp    = (int*)base;   base += (size_t)n * 4;
    int*   offs    = (int*)base;   base += (size_t)(n + 4) * 4;
    int*   cursor  = (int*)base;   base += (size_t)(n + 4) * 4;
    int*   bsum    = (int*)base;   base += (size_t)1024 * 4;
    int*   bhist   = (int*)base;   base += (size_t)512 * NBINS * 4;
    int*   bintot  = (int*)base;   base += (size_t)NBINS * 4;
    int*   binbase = (int*)base;   base += (size_t)NBINS * 4;
    int*   order   = (int*)base;   base += (size_t)n * 4;
    int*   slotof  = (int*)base;   base += (size_t)n * 4;
    float* dinv_s  = (float*)base; base += (size_t)n * 4;
    float* dinv_h  = (float*)base; base += (size_t)n * 4;
    int*   src     = (int*)base;   base += (size_t)E * 4;
    unsigned short* wt_hi = (unsigned short*)base; base += (size_t)21504 * 2 + 64;
    unsigned short* wt_lo = (unsigned short*)base; base += (size_t)21504 * 2 + 64;
    float* bufA    = (float*)base; base += (size_t)n * 64 * 4;
    float* bufB    = (float*)base; base += (size_t)n * 64 * 4;
    (void)ws_size;

    const int BLK = 256;
    const int nhb = ceil_div(n, SCAN_BLK);
    const int nb  = ceil_div(n + 1, SCAN_BLK);

    // --- degrees ---
    hipMemsetAsync(deg, 0, (size_t)n * 4, stream);
    deg_kernel<<<ceil_div(E, BLK), BLK, 0, stream>>>(col, deg, E);

    // --- counting sort by degree ---
    hist_kernel<<<nhb, SCAN_BLK, 0, stream>>>(deg, bhist, n);
    binscan_kernel<<<NBINS, 512, 0, stream>>>(bhist, bintot, nhb);
    base_scan_kernel<<<1, NBINS, 0, stream>>>(bintot, binbase);
    place_kernel<<<nhb, SCAN_BLK, 0, stream>>>(deg, bhist, binbase, order, slotof, n);
    dinvp_kernel<<<ceil_div(n, BLK), BLK, 0, stream>>>(deg, order, degp, dinv_s, dinv_h, n);

    // --- CSR build in slot space ---
    blk_reduce_kernel<<<nb, SCAN_BLK, 0, stream>>>(degp, bsum, n);
    bsum_scan_kernel<<<1, 1024, 0, stream>>>(bsum, nb);
    offs_kernel<<<nb, SCAN_BLK, 0, stream>>>(degp, bsum, offs, n);
    hipMemcpyAsync(cursor, offs, (size_t)n * 4, hipMemcpyDeviceToDevice, stream);
    csr_fill_kernel<<<ceil_div(E, BLK), BLK, 0, stream>>>(row, col, slotof, cursor, src, E);

    // --- W transpose + bf16 split (once per launch) ---
    WPtrs wp; wp.p[0] = We1; wp.p[1] = We2; wp.p[2] = We3;
    wp.p[3] = Wd1; wp.p[4] = Wd2; wp.p[5] = Wd3;
    wsplit_kernel<<<ceil_div(21504, BLK), BLK, 0, stream>>>(wp, wt_hi, wt_lo);

    // K1: u1 = dinv_s ⊙ (x[order] @ We1)          [PLAIN, 8 waves, 4 chunks of K=32]
    gemm_fused<128, 64, 8, M_PLAIN, false, false, true, true, false>
        <<<ceil_div(n, 128), 512, 0, stream>>>(
        x, wt_hi + 0, wt_lo + 0, nullptr, nullptr, nullptr, nullptr,
        nullptr, dinv_s, order, bufA, n);

    // K2: a1 = relu(dinv_s[c](Σu1+u1[c]) + be1); u2 = dinv_s ⊙ (a1 @ We2)  [SMOOTH, 2 chunks]
    gemm_fused<64, 32, 8, M_SMOOTH, false, false, true, false, false>
        <<<ceil_div(n, 128), 512, 0, stream>>>(
        bufA, wt_hi + 8192, wt_lo + 8192, be1, dinv_s, offs, src,
        nullptr, dinv_s, nullptr, bufB, n);

    // K3: a2 = relu(dinv_s[c](Σu2+u2[c]) + be2); u3 = dinv_s ⊙ (a2 @ We3)  [SMOOTH]
    gemm_fused<32, 16, 8, M_SMOOTH, false, false, true, false, false>
        <<<ceil_div(n, 128), 512, 0, stream>>>(
        bufB, wt_hi + 10240, wt_lo + 10240, be2, dinv_s, offs, src,
        nullptr, dinv_s, nullptr, bufA, n);

    // K4: Z' = dinv_h ⊙ (dinv_s[c](Σu3+u3[c]) + be3)   [standalone smooth gather]
    gather_tpd<16, false, false, true, true><<<ceil_div(n * 4, BLK), BLK, 0, stream>>>(
        bufA, offs, src, dinv_s, dinv_h, be3, bufB, n);

    // K5: P4 = dinv_h[c](2 relu(Z'[c]) - Σ relu(Z'[src])); u4 = dinv_h ⊙ relu(P4@Wd1+bd1)
    gemm_fused<16, 32, 8, M_SHARP_RELU, true, true, true, false, false>
        <<<ceil_div(n, 128), 512, 0, stream>>>(
        bufB, wt_hi + 10752, wt_lo + 10752, nullptr, dinv_h, offs, src,
        bd1, dinv_h, nullptr, bufA, n);

    // K6: P5 = dinv_h[c](2 u4[c] - Σ u4); u5 = dinv_h ⊙ relu(P5@Wd2+bd2)   [SHARP]
    gemm_fused<32, 64, 8, M_SHARP, true, true, true, false, false>
        <<<ceil_div(n, 128), 512, 0, stream>>>(
        bufA, wt_hi + 11264, wt_lo + 11264, nullptr, dinv_h, offs, src,
        bd2, dinv_h, nullptr, bufB, n);

    // K7: P6 = dinv_h[c](2 u5[c] - Σ u5); out[order] = P6 @ Wd3 + bd3      [SHARP, 2 chunks]
    gemm_fused<64, 128, 8, M_SHARP, true, false, false, false, true>
        <<<ceil_div(n, 128), 512, 0, stream>>>(
        bufB, wt_hi + 13312, wt_lo + 13312, nullptr, dinv_h, offs, src,
        bd3, nullptr, order, out, n);
}

// Round 11
// 250.107 us; speedup vs baseline: 3.1153x; 1.2696x over previous
//
#include <hip/hip_runtime.h>

// GALA graph autoencoder on MI355X — round 11: f16 intermediates (half the random-gather
// bytes), A_f16 x split-f16-W MFMA (2 passes, W accurate to 2^-21).
// Pipeline: degree counting-sort relabel -> slot space; weightless algebra
// prop = dinv ⊙ (A^T (dinv ⊙ h)) with self-loop folded; propagation fused into the
// consuming GEMM's A-staging; 4-way unrolled edge loops for memory-level parallelism.
// KC=32 chunks keep LDS <= 31KB -> 4 blocks x 8 waves per CU.

static inline int ceil_div(int a, int b) { return (a + b - 1) / b; }

#define SCAN_BLK 256
#define NBINS 64

typedef _Float16 f16;
typedef _Float16 f16x8 __attribute__((ext_vector_type(8)));
typedef float f32x4 __attribute__((ext_vector_type(4)));

__device__ __forceinline__ void relu4(float4& v) {
    v.x = fmaxf(v.x, 0.f); v.y = fmaxf(v.y, 0.f);
    v.z = fmaxf(v.z, 0.f); v.w = fmaxf(v.w, 0.f);
}

// ---------------- degree ----------------

__global__ void deg_kernel(const int* __restrict__ col, int* __restrict__ deg, int E) {
    int e = blockIdx.x * blockDim.x + threadIdx.x;
    if (e < E) atomicAdd(&deg[col[e]], 1);
}

// ---------------- counting sort by degree (block-aggregated, deterministic) ----------------

__global__ void hist_kernel(const int* __restrict__ deg, int* __restrict__ blockhist, int n) {
    __shared__ int lh[NBINS];
    if (threadIdx.x < NBINS) lh[threadIdx.x] = 0;
    __syncthreads();
    int i = blockIdx.x * SCAN_BLK + threadIdx.x;
    if (i < n) {
        int d = deg[i]; if (d >= NBINS) d = NBINS - 1;
        atomicAdd(&lh[d], 1);
    }
    __syncthreads();
    if (threadIdx.x < NBINS) blockhist[blockIdx.x * NBINS + threadIdx.x] = lh[threadIdx.x];
}

__global__ void binscan_kernel(int* __restrict__ blockhist, int* __restrict__ bintot, int nb) {
    __shared__ int s[512];
    int bin = blockIdx.x, t = threadIdx.x;
    int v = (t < nb) ? blockhist[t * NBINS + bin] : 0;
    s[t] = v;
    __syncthreads();
    for (int st = 1; st < 512; st <<= 1) {
        int a = (t >= st) ? s[t - st] : 0;
        __syncthreads();
        s[t] += a;
        __syncthreads();
    }
    if (t < nb) blockhist[t * NBINS + bin] = s[t] - v;
    if (t == 0) bintot[bin] = s[511];
}

__global__ void base_scan_kernel(const int* __restrict__ bintot, int* __restrict__ binbase) {
    __shared__ int s[NBINS];
    int t = threadIdx.x;
    int v = bintot[t];
    s[t] = v;
    __syncthreads();
    for (int st = 1; st < NBINS; st <<= 1) {
        int a = (t >= st) ? s[t - st] : 0;
        __syncthreads();
        s[t] += a;
        __syncthreads();
    }
    binbase[t] = s[t] - v;
}

__global__ void place_kernel(const int* __restrict__ deg, const int* __restrict__ blockhist,
                             const int* __restrict__ binbase, int* __restrict__ order,
                             int* __restrict__ slotof, int n) {
    __shared__ int lh[NBINS];
    if (threadIdx.x < NBINS) lh[threadIdx.x] = 0;
    __syncthreads();
    int i = blockIdx.x * SCAN_BLK + threadIdx.x;
    if (i < n) {
        int d = deg[i]; if (d >= NBINS) d = NBINS - 1;
        int r = atomicAdd(&lh[d], 1);
        int slot = binbase[d] + blockhist[blockIdx.x * NBINS + d] + r;
        order[slot] = i;
        slotof[i] = slot;
    }
}

__global__ void dinvp_kernel(const int* __restrict__ deg, const int* __restrict__ order,
                             int* __restrict__ degp, float* __restrict__ dinv_s,
                             float* __restrict__ dinv_h, int n) {
    int s = blockIdx.x * blockDim.x + threadIdx.x;
    if (s < n) {
        int dd = deg[order[s]];
        float d = (float)dd;
        degp[s] = dd;
        dinv_s[s] = rsqrtf(d + 1.0f);   // smooth: indeg + 1
        dinv_h[s] = rsqrtf(d + 2.0f);   // sharp:  indeg + 2
    }
}

// ---------------- CSR build (slot space) ----------------

__global__ void blk_reduce_kernel(const int* __restrict__ deg, int* __restrict__ bsum, int n) {
    __shared__ int s[SCAN_BLK];
    int i = blockIdx.x * SCAN_BLK + threadIdx.x;
    s[threadIdx.x] = (i < n) ? deg[i] : 0;
    __syncthreads();
    for (int st = SCAN_BLK / 2; st > 0; st >>= 1) {
        if (threadIdx.x < st) s[threadIdx.x] += s[threadIdx.x + st];
        __syncthreads();
    }
    if (threadIdx.x == 0) bsum[blockIdx.x] = s[0];
}

__global__ void bsum_scan_kernel(int* bsum, int nb) {
    __shared__ int s[1024];
    int t = threadIdx.x;
    int v0 = (t < nb) ? bsum[t] : 0;
    s[t] = v0;
    __syncthreads();
    for (int st = 1; st < 1024; st <<= 1) {
        int add = (t >= st) ? s[t - st] : 0;
        __syncthreads();
        s[t] += add;
        __syncthreads();
    }
    if (t < nb) bsum[t] = s[t] - v0;  // exclusive
}

__global__ void offs_kernel(const int* __restrict__ deg, const int* __restrict__ bpre,
                            int* __restrict__ offs, int n) {
    __shared__ int s[SCAN_BLK];
    int i = blockIdx.x * SCAN_BLK + threadIdx.x;
    int t = threadIdx.x;
    int v0 = (i < n) ? deg[i] : 0;
    s[t] = v0;
    __syncthreads();
    for (int st = 1; st < SCAN_BLK; st <<= 1) {
        int add = (t >= st) ? s[t - st] : 0;
        __syncthreads();
        s[t] += add;
        __syncthreads();
    }
    if (i <= n) offs[i] = bpre[blockIdx.x] + s[t] - v0;
}

__global__ void csr_fill_kernel(const int* __restrict__ row, const int* __restrict__ col,
                                const int* __restrict__ slotof, int* __restrict__ cursor,
                                int* __restrict__ src, int E) {
    int e = blockIdx.x * blockDim.x + threadIdx.x;
    if (e >= E) return;
    int cs = slotof[col[e]];
    int p = atomicAdd(&cursor[cs], 1);
    src[p] = slotof[row[e]];
}

// ---------------- W pre-transpose + split (f32 [DIN][DOUT] -> f16 hi/lo [DOUT][DIN]) ----------------

struct WPtrs { const float* p[6]; };

__global__ void wsplit_kernel(WPtrs wp, f16* __restrict__ wt_hi, f16* __restrict__ wt_lo) {
    const int din[6]  = {128, 64, 32, 16, 32, 64};
    const int dout[6] = {64, 32, 16, 32, 64, 128};
    const int off[6]  = {0, 8192, 10240, 10752, 11264, 13312};
    int t = blockIdx.x * blockDim.x + threadIdx.x;
    if (t >= 21504) return;
    int l = 0;
    while (l < 5 && t >= off[l + 1]) ++l;
    int idx = t - off[l];
    int c = idx / din[l], k = idx - c * din[l];
    float a = wp.p[l][k * dout[l] + c];
    f16 hi = (f16)a;
    f16 lo = (f16)(a - (float)hi);
    wt_hi[t] = hi;
    wt_lo[t] = lo;
}

// ---------------- fused gather + f16 MFMA GEMM ----------------
// Staging modes (per KC=32 k-chunk; chunking does not increase gather bytes, rows are
// read k-sliced):
//   PLAIN:      v = Af32[perm(row)][kslice]
//   SMOOTH:     v = relu( gdinv[r]*(Σ u[src] + u[r]) + gbias )
//   SHARP:      v = gdinv[r]*(2*u[r] - Σ u[src])
//   SHARP_RELU: same as SHARP, relu applied to gathered values
// C = A_f16 @ (W_hi + W_lo) via 2 MFMA passes (W to 2^-21). Epilogue: bias/relu/scale,
// output f16 (intermediates) or f32 (final).

#define M_PLAIN 0
#define M_SMOOTH 1
#define M_SHARP 2
#define M_SHARP_RELU 3

template <int DIN, int DOUT, int WAVES, int MODE, bool ADD_BIAS, bool RELU_OUT,
          bool SCALE_ROW, bool IN_PERM, bool OUT_PERM, bool OUT_F32>
__global__ __launch_bounds__(WAVES * 64) void gemm_fused(
        const float* __restrict__ Af, const f16* __restrict__ U,
        const f16* __restrict__ Wth, const f16* __restrict__ Wtl,
        const float* __restrict__ gbias, const float* __restrict__ gdinv,
        const int* __restrict__ offs, const int* __restrict__ srcv,
        const float* __restrict__ bias, const float* __restrict__ rs,
        const int* __restrict__ map, float* __restrict__ outf,
        f16* __restrict__ outh, int n) {
    constexpr int THREADS = WAVES * 64;
    constexpr int BM  = WAVES * 16;               // rows per block (128)
    constexpr int KC  = (DIN >= 32) ? 32 : DIN;   // real k per staged chunk
    constexpr int KCP = 32;                       // padded k (MFMA K=32)
    constexpr int NKC = DIN / KC;                 // chunks
    constexpr int NT  = DOUT / 16;                // n-tiles per wave
    constexpr int LDB = KCP * 2 + 16;             // LDS row stride = 80 B
    constexpr int AG  = KCP / 8;                  // f16x8 groups per row (4)
    __shared__ __align__(16) unsigned char lds[(BM + 2 * DOUT) * LDB];
    unsigned char* Asm = lds;
    unsigned char* Wh  = lds + (size_t)BM * LDB;
    unsigned char* Wl  = Wh + (size_t)DOUT * LDB;

    const int row0 = blockIdx.x * BM;
    const int lane = threadIdx.x & 63;
    const int wave = __builtin_amdgcn_readfirstlane((int)(threadIdx.x >> 6));
    const int l15 = lane & 15, lhi = lane >> 4;

    f32x4 acc[NT];
#pragma unroll
    for (int t = 0; t < NT; ++t) acc[t] = (f32x4){0.f, 0.f, 0.f, 0.f};

    for (int kc = 0; kc < NKC; ++kc) {
        const int kofs = kc * KC;
        // ---- stage A chunk ----
        for (int i = threadIdx.x; i < BM * AG; i += THREADS) {
            int r = i / AG, j = i % AG;
            f16x8 hv = {0, 0, 0, 0, 0, 0, 0, 0};
            int gr = row0 + r;
            if (gr < n && j * 8 < KC) {
                const int k8 = kofs + j * 8;
                if (MODE == M_PLAIN) {
                    int ar = IN_PERM ? map[gr] : gr;
                    float4 v0 = *(const float4*)(Af + (size_t)ar * DIN + k8);
                    float4 v1 = *(const float4*)(Af + (size_t)ar * DIN + k8 + 4);
                    hv[0] = (f16)v0.x; hv[1] = (f16)v0.y; hv[2] = (f16)v0.z; hv[3] = (f16)v0.w;
                    hv[4] = (f16)v1.x; hv[5] = (f16)v1.y; hv[6] = (f16)v1.z; hv[7] = (f16)v1.w;
                } else {
                    f16x8 s8 = *(const f16x8*)(U + (size_t)gr * DIN + k8);
                    float sf[8], g[8];
#pragma unroll
                    for (int q = 0; q < 8; ++q) {
                        sf[q] = (float)s8[q];
                        if (MODE == M_SHARP_RELU) sf[q] = fmaxf(sf[q], 0.f);
                        g[q] = 0.f;
                    }
                    int e = offs[gr], e1 = offs[gr + 1];
                    for (; e + 4 <= e1; e += 4) {
                        int r0 = srcv[e], r1 = srcv[e + 1], r2 = srcv[e + 2], r3 = srcv[e + 3];
                        f16x8 t0 = *(const f16x8*)(U + (size_t)r0 * DIN + k8);
                        f16x8 t1 = *(const f16x8*)(U + (size_t)r1 * DIN + k8);
                        f16x8 t2 = *(const f16x8*)(U + (size_t)r2 * DIN + k8);
                        f16x8 t3 = *(const f16x8*)(U + (size_t)r3 * DIN + k8);
#pragma unroll
                        for (int q = 0; q < 8; ++q) {
                            float a0 = (float)t0[q], a1 = (float)t1[q];
                            float a2 = (float)t2[q], a3 = (float)t3[q];
                            if (MODE == M_SHARP_RELU) {
                                a0 = fmaxf(a0, 0.f); a1 = fmaxf(a1, 0.f);
                                a2 = fmaxf(a2, 0.f); a3 = fmaxf(a3, 0.f);
                            }
                            g[q] += (a0 + a1) + (a2 + a3);
                        }
                    }
                    for (; e < e1; ++e) {
                        f16x8 t0 = *(const f16x8*)(U + (size_t)srcv[e] * DIN + k8);
#pragma unroll
                        for (int q = 0; q < 8; ++q) {
                            float a0 = (float)t0[q];
                            if (MODE == M_SHARP_RELU) a0 = fmaxf(a0, 0.f);
                            g[q] += a0;
                        }
                    }
                    float dv = gdinv[gr];
#pragma unroll
                    for (int q = 0; q < 8; ++q) {
                        float v;
                        if (MODE == M_SMOOTH) {
                            v = fmaf(dv, g[q] + sf[q], gbias[k8 + q]);
                            v = fmaxf(v, 0.f);
                        } else {
                            v = dv * (2.f * sf[q] - g[q]);
                        }
                        hv[q] = (f16)v;
                    }
                }
            }
            *(f16x8*)(Asm + (size_t)r * LDB + j * 16) = hv;
        }
        // ---- stage W chunk (transposed + split in global) ----
        for (int i = threadIdx.x; i < DOUT * AG; i += THREADS) {
            int c = i / AG, j = i % AG;
            f16x8 h8 = {0, 0, 0, 0, 0, 0, 0, 0}, l8 = {0, 0, 0, 0, 0, 0, 0, 0};
            if (j * 8 < KC) {
                h8 = *(const f16x8*)(Wth + (size_t)c * DIN + kofs + j * 8);
                l8 = *(const f16x8*)(Wtl + (size_t)c * DIN + kofs + j * 8);
            }
            *(f16x8*)(Wh + (size_t)c * LDB + j * 16) = h8;
            *(f16x8*)(Wl + (size_t)c * LDB + j * 16) = l8;
        }
        __syncthreads();

        // ---- MFMA: acc += a*wh + a*wl ----
        f16x8 a = *(const f16x8*)(Asm + (size_t)(wave * 16 + l15) * LDB + lhi * 16);
#pragma unroll
        for (int t = 0; t < NT; ++t) {
            f16x8 bh = *(const f16x8*)(Wh + (size_t)(t * 16 + l15) * LDB + lhi * 16);
            f16x8 bl = *(const f16x8*)(Wl + (size_t)(t * 16 + l15) * LDB + lhi * 16);
            acc[t] = __builtin_amdgcn_mfma_f32_16x16x32_f16(a, bh, acc[t], 0, 0, 0);
            acc[t] = __builtin_amdgcn_mfma_f32_16x16x32_f16(a, bl, acc[t], 0, 0, 0);
        }
        if (NKC > 1) __syncthreads();
    }

    // ---- epilogue: C/D layout col=l&15, row=(l>>4)*4+r ----
    const int rbase = row0 + wave * 16 + (lhi << 2);
    float rsv[4]; int om[4];
#pragma unroll
    for (int r = 0; r < 4; ++r) {
        int row = rbase + r;
        bool ok = row < n;
        rsv[r] = (SCALE_ROW && ok) ? rs[row] : 1.0f;
        om[r] = ok ? (OUT_PERM ? map[row] : row) : -1;
    }
#pragma unroll
    for (int t = 0; t < NT; ++t) {
        int colb = t * 16 + l15;
        float b = ADD_BIAS ? bias[colb] : 0.f;
#pragma unroll
        for (int r = 0; r < 4; ++r) {
            if (om[r] < 0) continue;
            float v = acc[t][r] + b;
            if (RELU_OUT) v = fmaxf(v, 0.f);
            if (SCALE_ROW) v *= rsv[r];
            if (OUT_F32) outf[(size_t)om[r] * DOUT + colb] = v;
            else         outh[(size_t)om[r] * DOUT + colb] = (f16)v;
        }
    }
}

// ---------------- standalone smooth gather d=16, f16 -> f16 (L3->L4 boundary) ----------------
// Z' = ps[c] * ( dinv[c]*(Σ u[src] + u[c]) + bias )

__global__ __launch_bounds__(256) void gather16(
        const f16* __restrict__ u, const int* __restrict__ offs,
        const int* __restrict__ src, const float* __restrict__ dinv,
        const float* __restrict__ ps, const float* __restrict__ bias,
        f16* __restrict__ out, int n) {
    int idx = blockIdx.x * blockDim.x + threadIdx.x;
    int node = idx >> 1;
    if (node >= n) return;
    int d8 = (idx & 1) * 8;

    f16x8 s8 = *(const f16x8*)(u + (size_t)node * 16 + d8);
    float g[8];
#pragma unroll
    for (int q = 0; q < 8; ++q) g[q] = 0.f;
    int e = offs[node], e1 = offs[node + 1];
    for (; e + 4 <= e1; e += 4) {
        int r0 = src[e], r1 = src[e + 1], r2 = src[e + 2], r3 = src[e + 3];
        f16x8 t0 = *(const f16x8*)(u + (size_t)r0 * 16 + d8);
        f16x8 t1 = *(const f16x8*)(u + (size_t)r1 * 16 + d8);
        f16x8 t2 = *(const f16x8*)(u + (size_t)r2 * 16 + d8);
        f16x8 t3 = *(const f16x8*)(u + (size_t)r3 * 16 + d8);
#pragma unroll
        for (int q = 0; q < 8; ++q)
            g[q] += ((float)t0[q] + (float)t1[q]) + ((float)t2[q] + (float)t3[q]);
    }
    for (; e < e1; ++e) {
        f16x8 t0 = *(const f16x8*)(u + (size_t)src[e] * 16 + d8);
#pragma unroll
        for (int q = 0; q < 8; ++q) g[q] += (float)t0[q];
    }
    float dv = dinv[node], p = ps[node];
    f16x8 o;
#pragma unroll
    for (int q = 0; q < 8; ++q) {
        float v = p * (fmaf(dv, g[q] + (float)s8[q], bias[d8 + q]));
        o[q] = (f16)v;
    }
    *(f16x8*)(out + (size_t)node * 16 + d8) = o;
}

// ---------------- host orchestration ----------------

extern "C" void kernel_launch(void* const* d_in, const int* in_sizes, int n_in,
                              void* d_out, int out_size, void* d_ws, size_t ws_size,
                              hipStream_t stream) {
    const int T = 128;
    const int n = in_sizes[0] / T;        // 100000
    const int E = in_sizes[1] / 2;        // 600000

    const float* x   = (const float*)d_in[0];
    const int* eidx  = (const int*)d_in[1];
    const int* row   = eidx;
    const int* col   = eidx + E;
    const float* We1 = (const float*)d_in[2];
    const float* be1 = (const float*)d_in[3];
    const float* We2 = (const float*)d_in[4];
    const float* be2 = (const float*)d_in[5];
    const float* We3 = (const float*)d_in[6];
    const float* be3 = (const float*)d_in[7];
    const float* Wd1 = (const float*)d_in[8];
    const float* bd1 = (const float*)d_in[9];
    const float* Wd2 = (const float*)d_in[10];
    const float* bd2 = (const float*)d_in[11];
    const float* Wd3 = (const float*)d_in[12];
    const float* bd3 = (const float*)d_in[13];
    float* out = (float*)d_out;

    // workspace layout (all 16B aligned)
    char* base = (char*)d_ws;
    int*   deg     = (int*)base;   base += (size_t)n * 4;
    int*   degp    = (int*)base;   base += (size_t)n * 4;
    int*   offs    = (int*)base;   base += (size_t)(n + 4) * 4;
    int*   cursor  = (int*)base;   base += (size_t)(n + 4) * 4;
    int*   bsum    = (int*)base;   base += (size_t)1024 * 4;
    int*   bhist   = (int*)base;   base += (size_t)512 * NBINS * 4;
    int*   bintot  = (int*)base;   base += (size_t)NBINS * 4;
    int*   binbase = (int*)base;   base += (size_t)NBINS * 4;
    int*   order   = (int*)base;   base += (size_t)n * 4;
    int*   slotof  = (int*)base;   base += (size_t)n * 4;
    float* dinv_s  = (float*)base; base += (size_t)n * 4;
    float* dinv_h  = (float*)base; base += (size_t)n * 4;
    int*   src     = (int*)base;   base += (size_t)E * 4;
    f16*   wt_hi   = (f16*)base;   base += (size_t)21504 * 2 + 64;
    f16*   wt_lo   = (f16*)base;   base += (size_t)21504 * 2 + 64;
    f16*   bufA    = (f16*)base;   base += (size_t)n * 64 * 2;
    f16*   bufB    = (f16*)base;   base += (size_t)n * 64 * 2;
    (void)ws_size;

    const int BLK = 256;
    const int nhb = ceil_div(n, SCAN_BLK);
    const int nb  = ceil_div(n + 1, SCAN_BLK);

    // --- degrees ---
    hipMemsetAsync(deg, 0, (size_t)n * 4, stream);
    deg_kernel<<<ceil_div(E, BLK), BLK, 0, stream>>>(col, deg, E);

    // --- counting sort by degree ---
    hist_kernel<<<nhb, SCAN_BLK, 0, stream>>>(deg, bhist, n);
    binscan_kernel<<<NBINS, 512, 0, stream>>>(bhist, bintot, nhb);
    base_scan_kernel<<<1, NBINS, 0, stream>>>(bintot, binbase);
    place_kernel<<<nhb, SCAN_BLK, 0, stream>>>(deg, bhist, binbase, order, slotof, n);
    dinvp_kernel<<<ceil_div(n, BLK), BLK, 0, stream>>>(deg, order, degp, dinv_s, dinv_h, n);

    // --- CSR build in slot space ---
    blk_reduce_kernel<<<nb, SCAN_BLK, 0, stream>>>(degp, bsum, n);
    bsum_scan_kernel<<<1, 1024, 0, stream>>>(bsum, nb);
    offs_kernel<<<nb, SCAN_BLK, 0, stream>>>(degp, bsum, offs, n);
    hipMemcpyAsync(cursor, offs, (size_t)n * 4, hipMemcpyDeviceToDevice, stream);
    csr_fill_kernel<<<ceil_div(E, BLK), BLK, 0, stream>>>(row, col, slotof, cursor, src, E);

    // --- W transpose + f16 split (once per launch) ---
    WPtrs wp; wp.p[0] = We1; wp.p[1] = We2; wp.p[2] = We3;
    wp.p[3] = Wd1; wp.p[4] = Wd2; wp.p[5] = Wd3;
    wsplit_kernel<<<ceil_div(21504, BLK), BLK, 0, stream>>>(wp, wt_hi, wt_lo);

    const int ggrid = ceil_div(n, 128);

    // K1: u1 = dinv_s ⊙ (x[order] @ We1)                     [PLAIN, 4 chunks]
    gemm_fused<128, 64, 8, M_PLAIN, false, false, true, true, false, false>
        <<<ggrid, 512, 0, stream>>>(
        x, nullptr, wt_hi + 0, wt_lo + 0, nullptr, nullptr, nullptr, nullptr,
        nullptr, dinv_s, order, nullptr, bufA, n);

    // K2: a1 = relu(dinv_s[c](Σu1+u1[c]) + be1); u2 = dinv_s ⊙ (a1 @ We2)   [SMOOTH]
    gemm_fused<64, 32, 8, M_SMOOTH, false, false, true, false, false, false>
        <<<ggrid, 512, 0, stream>>>(
        nullptr, bufA, wt_hi + 8192, wt_lo + 8192, be1, dinv_s, offs, src,
        nullptr, dinv_s, nullptr, nullptr, bufB, n);

    // K3: a2 = relu(dinv_s[c](Σu2+u2[c]) + be2); u3 = dinv_s ⊙ (a2 @ We3)   [SMOOTH]
    gemm_fused<32, 16, 8, M_SMOOTH, false, false, true, false, false, false>
        <<<ggrid, 512, 0, stream>>>(
        nullptr, bufB, wt_hi + 10240, wt_lo + 10240, be2, dinv_s, offs, src,
        nullptr, dinv_s, nullptr, nullptr, bufA, n);

    // K4: Z' = dinv_h ⊙ (dinv_s[c](Σu3+u3[c]) + be3)         [standalone gather]
    gather16<<<ceil_div(n * 2, BLK), BLK, 0, stream>>>(
        bufA, offs, src, dinv_s, dinv_h, be3, bufB, n);

    // K5: P4 = dinv_h[c](2 relu(Z'[c]) - Σ relu(Z'[src])); u4 = dinv_h ⊙ relu(P4@Wd1+bd1)
    gemm_fused<16, 32, 8, M_SHARP_RELU, true, true, true, false, false, false>
        <<<ggrid, 512, 0, stream>>>(
        nullptr, bufB, wt_hi + 10752, wt_lo + 10752, nullptr, dinv_h, offs, src,
        bd1, dinv_h, nullptr, nullptr, bufA, n);

    // K6: P5 = dinv_h[c](2 u4[c] - Σ u4); u5 = dinv_h ⊙ relu(P5@Wd2+bd2)    [SHARP]
    gemm_fused<32, 64, 8, M_SHARP, true, true, true, false, false, false>
        <<<ggrid, 512, 0, stream>>>(
        nullptr, bufA, wt_hi + 11264, wt_lo + 11264, nullptr, dinv_h, offs, src,
        bd2, dinv_h, nullptr, nullptr, bufB, n);

    // K7: P6 = dinv_h[c](2 u5[c] - Σ u5); out[order] = P6 @ Wd3 + bd3       [SHARP, 2 chunks]
    gemm_fused<64, 128, 8, M_SHARP, true, false, false, false, true, true>
        <<<ggrid, 512, 0, stream>>>(
        nullptr, bufB, wt_hi + 13312, wt_lo + 13312, nullptr, dinv_h, offs, src,
        bd3, nullptr, order, out, nullptr, n);
}